// Round 4
// baseline (1576.289 us; speedup 1.0000x reference)
//
#include <hip/hip_runtime.h>
#include <hip/hip_bf16.h>

#define NB 16
#define NN 2048
#define KNNK 16
#define MM 1024
#define RC1 (NB*NN*KNNK)   // 524288 conv1 BN rows
#define RC2 (NB*MM*KNNK)   // 262144 conv2 BN rows

typedef unsigned long long u64;

__device__ __forceinline__ float frn_mul(float a, float b){ return __fmul_rn(a,b); }
__device__ __forceinline__ float frn_add(float a, float b){ return __fadd_rn(a,b); }
__device__ __forceinline__ float frn_sub(float a, float b){ return __fsub_rn(a,b); }
__device__ __forceinline__ float silu_f(float x){ return x / (1.0f + __expf(-x)); }

__device__ __forceinline__ unsigned f32_sortable(float f){
  unsigned u = __float_as_uint(f);
  return u ^ ((unsigned)((int)u >> 31) | 0x80000000u);
}

__device__ __forceinline__ void atomicMaxF(unsigned* addr, float v){
  if (v >= 0.f) atomicMax((int*)addr, (int)__float_as_uint(v));
  else          atomicMin(addr, __float_as_uint(v));
}
__device__ __forceinline__ void atomicMinF(unsigned* addr, float v){
  if (v >= 0.f) atomicMin((int*)addr, (int)__float_as_uint(v));
  else          atomicMax(addr, __float_as_uint(v));
}

__global__ __launch_bounds__(256) void init_kernel(float* stats1, float* stats2a, float* stats2b,
                                                   unsigned* gmax, unsigned* gmin){
  int t = blockIdx.x*256 + threadIdx.x;
  if (t < 128) stats1[t] = 0.f;
  if (t < 256) stats2a[t] = 0.f;
  if (t < 512) stats2b[t] = 0.f;
  if (t < 4096){ gmax[t] = 0xFF800000u; gmin[t] = 0x7F800000u; }
}

// ---- knn chunk: 256 query threads vs CHUNK staged points; sorted u64 top-16 ----
template<int CHUNK>
__device__ __forceinline__ void knn_chunk_body(const float* __restrict__ pos_b, int qbase, int jbase,
                                               float4* sm, u64* __restrict__ out, int tid){
  for (int t = tid; t < CHUNK; t += 256){
    const float* p = pos_b + (size_t)(jbase + t)*3;
    float x = p[0], y = p[1], z = p[2];
    float n2 = frn_add(frn_add(frn_mul(x,x), frn_mul(y,y)), frn_mul(z,z));
    sm[t] = make_float4(x,y,z,n2);
  }
  __syncthreads();
  int i = qbase + tid;
  const float* qp = pos_b + (size_t)i*3;
  float xi = qp[0], yi = qp[1], zi = qp[2];
  float n2i = frn_add(frn_add(frn_mul(xi,xi), frn_mul(yi,yi)), frn_mul(zi,zi));
  u64 best[KNNK];
#pragma unroll
  for (int p = 0; p < KNNK; ++p) best[p] = ~0ull;
  for (int jj = 0; jj < CHUNK; ++jj){
    float4 v = sm[jj];
    float e = frn_add(frn_add(frn_mul(xi,v.x), frn_mul(yi,v.y)), frn_mul(zi,v.z));
    float d = frn_sub(frn_add(n2i, v.w), frn_mul(2.0f, e));
    u64 key = ((u64)f32_sortable(d) << 32) | (unsigned)(jbase + jj);
    if (key < best[KNNK-1]){
      u64 cur = key;
#pragma unroll
      for (int p = 0; p < KNNK; ++p){
        u64 mn = best[p] < cur ? best[p] : cur;
        u64 mx = best[p] < cur ? cur : best[p];
        best[p] = mn; cur = mx;
      }
    }
  }
#pragma unroll
  for (int p = 0; p < KNNK; ++p) out[p] = best[p];
}

// ---- K0: blocks 0..15 = FPS (register points, DPP argmax), 16..271 = knn1 chunks ----
__global__ __launch_bounds__(256) void k0_fps_knn1(const float* __restrict__ pos,
    int* __restrict__ idxf, float* __restrict__ pos2, u64* __restrict__ pknn1){
  __shared__ __align__(16) char smem[16*1024];
  int tid = threadIdx.x;
  if (blockIdx.x < 16){
    int b = blockIdx.x;
    float* wredf = (float*)smem;        // [2][4][8] floats = 256 B
    const float* pb = pos + (size_t)b*NN*3;
    float X[8], Y[8], Z[8], MD[8];
#pragma unroll
    for (int q = 0; q < 8; ++q){
      int p = tid + 256*q;
      X[q] = pb[p*3+0]; Y[q] = pb[p*3+1]; Z[q] = pb[p*3+2];
    }
    float qx = pb[0], qy = pb[1], qz = pb[2];
#pragma unroll
    for (int q = 0; q < 8; ++q){
      float dx = frn_sub(X[q],qx), dy = frn_sub(Y[q],qy), dz = frn_sub(Z[q],qz);
      MD[q] = frn_add(frn_add(frn_mul(dx,dx), frn_mul(dy,dy)), frn_mul(dz,dz));
    }
    if (tid == 0){
      idxf[b*MM + 0] = 0;
      pos2[(size_t)(b*MM+0)*3+0] = qx;
      pos2[(size_t)(b*MM+0)*3+1] = qy;
      pos2[(size_t)(b*MM+0)*3+2] = qz;
    }
    int wv = tid >> 6;
    for (int s = 1; s < MM; ++s){
      // lane-local argmax over 8 points (u64 key = dist<<32 | ~p)
      u64 bk = ((u64)__float_as_uint(MD[0]) << 32) | (unsigned)(~tid);
      float bx = X[0], by = Y[0], bz = Z[0];
#pragma unroll
      for (int q = 1; q < 8; ++q){
        u64 kq = ((u64)__float_as_uint(MD[q]) << 32) | (unsigned)(~(tid + 256*q));
        if (kq > bk){ bk = kq; bx = X[q]; by = Y[q]; bz = Z[q]; }
      }
      // in-wave max-reduce carrying coords: 4 DPP + swizzle(xor16) + shfl(xor32)
#define FPS_COMB(PLO,PHI,PX,PY,PZ) { \
        unsigned plo_=(PLO), phi_=(PHI); float px_=(PX), py_=(PY), pz_=(PZ); \
        u64 pk_ = ((u64)phi_ << 32) | plo_; \
        if (pk_ > bk){ bk = pk_; bx = px_; by = py_; bz = pz_; } }
#define FPS_DPP(CTRL) { \
        unsigned lo__=(unsigned)bk, hi__=(unsigned)(bk>>32); \
        FPS_COMB((unsigned)__builtin_amdgcn_update_dpp((int)lo__,(int)lo__,CTRL,0xF,0xF,false), \
                 (unsigned)__builtin_amdgcn_update_dpp((int)hi__,(int)hi__,CTRL,0xF,0xF,false), \
                 __uint_as_float((unsigned)__builtin_amdgcn_update_dpp((int)__float_as_uint(bx),(int)__float_as_uint(bx),CTRL,0xF,0xF,false)), \
                 __uint_as_float((unsigned)__builtin_amdgcn_update_dpp((int)__float_as_uint(by),(int)__float_as_uint(by),CTRL,0xF,0xF,false)), \
                 __uint_as_float((unsigned)__builtin_amdgcn_update_dpp((int)__float_as_uint(bz),(int)__float_as_uint(bz),CTRL,0xF,0xF,false))) }
      FPS_DPP(0xB1)   // quad_perm [1,0,3,2]  xor1
      FPS_DPP(0x4E)   // quad_perm [2,3,0,1]  xor2
      FPS_DPP(0x124)  // row_ror:4
      FPS_DPP(0x128)  // row_ror:8
      {
        unsigned lo__=(unsigned)bk, hi__=(unsigned)(bk>>32);
        FPS_COMB((unsigned)__builtin_amdgcn_ds_swizzle((int)lo__,0x401F),
                 (unsigned)__builtin_amdgcn_ds_swizzle((int)hi__,0x401F),
                 __uint_as_float((unsigned)__builtin_amdgcn_ds_swizzle((int)__float_as_uint(bx),0x401F)),
                 __uint_as_float((unsigned)__builtin_amdgcn_ds_swizzle((int)__float_as_uint(by),0x401F)),
                 __uint_as_float((unsigned)__builtin_amdgcn_ds_swizzle((int)__float_as_uint(bz),0x401F)))
      }
      {
        unsigned lo__=(unsigned)bk, hi__=(unsigned)(bk>>32);
        FPS_COMB((unsigned)__shfl_xor((int)lo__,32),
                 (unsigned)__shfl_xor((int)hi__,32),
                 __shfl_xor(bx,32), __shfl_xor(by,32), __shfl_xor(bz,32))
      }
#undef FPS_DPP
      // cross-wave via LDS, single barrier, parity double-buffer
      int par = s & 1;
      if ((tid & 63) == 0){
        float* wp_ = wredf + (par*4 + wv)*8;
        wp_[0] = __uint_as_float((unsigned)bk);
        wp_[1] = __uint_as_float((unsigned)(bk>>32));
        wp_[2] = bx; wp_[3] = by; wp_[4] = bz;
      }
      __syncthreads();
      u64 K = 0; float wx = 0.f, wy = 0.f, wz = 0.f;
#pragma unroll
      for (int w4 = 0; w4 < 4; ++w4){
        const float* rp = wredf + (par*4 + w4)*8;
        unsigned lo = __float_as_uint(rp[0]), hi = __float_as_uint(rp[1]);
        u64 kk = ((u64)hi << 32) | lo;
        if (kk > K){ K = kk; wx = rp[2]; wy = rp[3]; wz = rp[4]; }
      }
#undef FPS_COMB
      unsigned wp = ~(unsigned)K;
      if (tid == 0){
        idxf[b*MM + s] = (int)wp;
        pos2[(size_t)(b*MM+s)*3+0] = wx;
        pos2[(size_t)(b*MM+s)*3+1] = wy;
        pos2[(size_t)(b*MM+s)*3+2] = wz;
      }
#pragma unroll
      for (int q = 0; q < 8; ++q){
        float dx = frn_sub(X[q],wx), dy = frn_sub(Y[q],wy), dz = frn_sub(Z[q],wz);
        float d = frn_add(frn_add(frn_mul(dx,dx), frn_mul(dy,dy)), frn_mul(dz,dz));
        MD[q] = fminf(MD[q], d);
      }
    }
  } else {
    int cid = blockIdx.x - 16;          // 0..255
    int b = cid >> 4;
    int rblk = (cid >> 1) & 7;
    int ch = cid & 1;
    float4* sm = (float4*)smem;         // 1024 * 16B
    const float* pos_b = pos + (size_t)b*NN*3;
    int i = rblk*256 + tid;
    u64* out = pknn1 + ((size_t)(b*NN + i)*2 + ch)*KNNK;
    knn_chunk_body<1024>(pos_b, rblk*256, ch*1024, sm, out, tid);
  }
}

// ---- K1: blocks 0..127 = merge1 (2-way), blocks 128..383 = knn2 chunks ----
__global__ __launch_bounds__(256) void k1_merge1_knn2(const u64* __restrict__ pknn1,
    int* __restrict__ idx1, const float* __restrict__ pos2, u64* __restrict__ pknn2){
  __shared__ __align__(16) float4 sm[256];
  int tid = threadIdx.x;
  if (blockIdx.x < 128){
    int row = blockIdx.x*256 + tid;     // 32768 rows
    const u64* A = pknn1 + (size_t)row*32;
    const u64* B = A + 16;
    int ia = 0, ib = 0;
    int* op = idx1 + (size_t)row*KNNK;
#pragma unroll
    for (int p = 0; p < KNNK; ++p){
      u64 ka = A[ia], kb = B[ib];
      if (ka < kb){ op[p] = (int)(unsigned)ka; ++ia; }
      else        { op[p] = (int)(unsigned)kb; ++ib; }
    }
  } else {
    int cid = blockIdx.x - 128;         // 0..255
    int b = cid >> 4;
    int rblk = (cid >> 2) & 3;
    int ch = cid & 3;
    const float* pos_b = pos2 + (size_t)b*MM*3;
    int i = rblk*256 + tid;
    u64* out = pknn2 + ((size_t)(b*MM + i)*4 + ch)*KNNK;
    knn_chunk_body<256>(pos_b, rblk*256, ch*256, sm, out, tid);
  }
}

// ---- K2: blocks 0..63 = merge2 (4-way), blocks 64..1087 = conv1 stats ----
__global__ __launch_bounds__(256) void k2_merge2_c1stats(const u64* __restrict__ pknn2,
    int* __restrict__ idx2, const float* __restrict__ pos, const int* __restrict__ idx1,
    const float* __restrict__ W1, const float* __restrict__ b1, float* __restrict__ stats1){
  __shared__ float red[4][64][2];
  int tid = threadIdx.x;
  if (blockIdx.x < 64){
    int row = blockIdx.x*256 + tid;     // 16384 rows
    const u64* L = pknn2 + (size_t)row*64;
    int o0=0, o1=0, o2=0, o3=0;
    int* op = idx2 + (size_t)row*KNNK;
#pragma unroll
    for (int p = 0; p < KNNK; ++p){
      u64 k0 = L[o0], k1 = L[16+o1], k2 = L[32+o2], k3 = L[48+o3];
      u64 m01 = k0 < k1 ? k0 : k1;
      u64 m23 = k2 < k3 ? k2 : k3;
      u64 m = m01 < m23 ? m01 : m23;
      op[p] = (int)(unsigned)m;
      o0 += (m == k0); o1 += (m == k1); o2 += (m == k2); o3 += (m == k3);
    }
    return;
  }
  int lane = tid & 63, wv = tid >> 6;
  int wave = (blockIdx.x - 64)*4 + wv;  // 0..4095, 8 rows each
  float w[6];
#pragma unroll
  for (int f = 0; f < 6; ++f) w[f] = W1[f*64 + lane];
  float bias = b1[lane];
  float ssum = 0.f, ssq = 0.f;
  for (int r = 0; r < 8; ++r){
    int row = wave*8 + r;
    int b = row >> 11, ii = row & 2047;
    const float* pi = pos + ((size_t)(b*NN + ii))*3;
    float xi = pi[0], yi = pi[1], zi = pi[2];
    const int* ip = idx1 + (size_t)row * KNNK;
#pragma unroll 4
    for (int k = 0; k < KNNK; ++k){
      int j = ip[k];
      const float* pj = pos + ((size_t)(b*NN + j))*3;
      float xj = pj[0], yj = pj[1], zj = pj[2];
      float y = bias;
      y = fmaf(xj, w[0], y); y = fmaf(yj, w[1], y); y = fmaf(zj, w[2], y);
      y = fmaf(xj - xi, w[3], y); y = fmaf(yj - yi, w[4], y); y = fmaf(zj - zi, w[5], y);
      ssum += y; ssq = fmaf(y, y, ssq);
    }
  }
  red[wv][lane][0] = ssum; red[wv][lane][1] = ssq;
  __syncthreads();
  if (tid < 64){
    float s = red[0][lane][0]+red[1][lane][0]+red[2][lane][0]+red[3][lane][0];
    float q = red[0][lane][1]+red[1][lane][1]+red[2][lane][1]+red[3][lane][1];
    atomicAdd(&stats1[lane], s);
    atomicAdd(&stats1[64+lane], q);
  }
}

__global__ __launch_bounds__(256) void conv1_apply_kernel(
    const float* __restrict__ pos, const int* __restrict__ idx1,
    const float* __restrict__ W1, const float* __restrict__ b1,
    const float* __restrict__ g1, const float* __restrict__ be1,
    const float* __restrict__ stats1, float* __restrict__ h){
  int lane = threadIdx.x & 63, wv = threadIdx.x >> 6;
  int wave = blockIdx.x*4 + wv;
  float w[6];
#pragma unroll
  for (int f = 0; f < 6; ++f) w[f] = W1[f*64 + lane];
  float bias = b1[lane];
  const float inv = 1.0f / (float)RC1;
  float mu = stats1[lane] * inv;
  float var = fmaxf(stats1[64+lane]*inv - mu*mu, 0.f);
  float sc = rsqrtf(var + 1e-5f) * g1[lane];
  float sh = be1[lane] - mu*sc;
  for (int r = 0; r < 8; ++r){
    int row = wave*8 + r;
    int b = row >> 11, ii = row & 2047;
    const float* pi = pos + ((size_t)(b*NN + ii))*3;
    float xi = pi[0], yi = pi[1], zi = pi[2];
    const int* ip = idx1 + (size_t)row * KNNK;
    float ymn = INFINITY, ymx = -INFINITY;
#pragma unroll 4
    for (int k = 0; k < KNNK; ++k){
      int j = ip[k];
      const float* pj = pos + ((size_t)(b*NN + j))*3;
      float xj = pj[0], yj = pj[1], zj = pj[2];
      float y = bias;
      y = fmaf(xj, w[0], y); y = fmaf(yj, w[1], y); y = fmaf(zj, w[2], y);
      y = fmaf(xj - xi, w[3], y); y = fmaf(yj - yi, w[4], y); y = fmaf(zj - zi, w[5], y);
      ymn = fminf(ymn, y); ymx = fmaxf(ymx, y);
    }
    h[((size_t)row << 6) + lane] = fmaxf(silu_f(fmaf(ymx, sc, sh)), silu_f(fmaf(ymn, sc, sh)));
  }
}

// ---- conv2a: 8 rows share each LDS weight read; double indirection replaces hs ----
__global__ __launch_bounds__(256) void conv2a_kernel(
    const float* __restrict__ h, const int* __restrict__ idxf,
    const float* __restrict__ pos2, const int* __restrict__ idx2,
    const float* __restrict__ W2a, const float* __restrict__ b2a,
    float* __restrict__ stats2a, __hip_bfloat16* __restrict__ y2a){
  __shared__ float Wl[67*128];
  __shared__ float red[4][64][4];
  for (int t = threadIdx.x; t < 67*128; t += 256) Wl[t] = W2a[t];
  __syncthreads();
  int lane = threadIdx.x & 63, wv = threadIdx.x >> 6;
  int wave = blockIdx.x*4 + wv;                 // 0..4095, 64 rows each
  float bias0 = b2a[lane], bias1 = b2a[64+lane];
  float ssum0=0, ssq0=0, ssum1=0, ssq1=0;
  for (int r8 = 0; r8 < 8; ++r8){
    int row0 = wave*64 + r8*8;
    int b = row0 >> 14;
    int m = (row0 >> 4) & 1023;                 // 8 rows stay within one m (row0 % 16 in {0,8})
    int j[8], q[8];
#pragma unroll
    for (int rr = 0; rr < 8; ++rr) j[rr] = idx2[row0 + rr];
#pragma unroll
    for (int rr = 0; rr < 8; ++rr) q[rr] = idxf[b*MM + j[rr]];
    const float4* hp[8];
#pragma unroll
    for (int rr = 0; rr < 8; ++rr) hp[rr] = (const float4*)(h + ((size_t)(b*NN + q[rr]) << 6));
    float y0[8], y1[8];
#pragma unroll
    for (int rr = 0; rr < 8; ++rr){ y0[rr] = bias0; y1[rr] = bias1; }
#pragma unroll
    for (int f4 = 0; f4 < 16; ++f4){
      float4 v[8];
#pragma unroll
      for (int rr = 0; rr < 8; ++rr) v[rr] = hp[rr][f4];
#pragma unroll
      for (int e = 0; e < 4; ++e){
        float w0_ = Wl[(f4*4+e)*128 + lane], w1_ = Wl[(f4*4+e)*128 + 64 + lane];
#pragma unroll
        for (int rr = 0; rr < 8; ++rr){
          float a = (e==0) ? v[rr].x : (e==1) ? v[rr].y : (e==2) ? v[rr].z : v[rr].w;
          y0[rr] = fmaf(a, w0_, y0[rr]); y1[rr] = fmaf(a, w1_, y1[rr]);
        }
      }
    }
    const float* pm = pos2 + ((size_t)(b*MM + m))*3;
    float pmx = pm[0], pmy = pm[1], pmz = pm[2];
    float dxx[8], dyy[8], dzz[8];
#pragma unroll
    for (int rr = 0; rr < 8; ++rr){
      const float* pj = pos2 + ((size_t)(b*MM + j[rr]))*3;
      dxx[rr] = pj[0]-pmx; dyy[rr] = pj[1]-pmy; dzz[rr] = pj[2]-pmz;
    }
#pragma unroll
    for (int e = 0; e < 3; ++e){
      float w0_ = Wl[(64+e)*128 + lane], w1_ = Wl[(64+e)*128 + 64 + lane];
#pragma unroll
      for (int rr = 0; rr < 8; ++rr){
        float a = (e==0) ? dxx[rr] : (e==1) ? dyy[rr] : dzz[rr];
        y0[rr] = fmaf(a, w0_, y0[rr]); y1[rr] = fmaf(a, w1_, y1[rr]);
      }
    }
#pragma unroll
    for (int rr = 0; rr < 8; ++rr){
      ssum0 += y0[rr]; ssq0 = fmaf(y0[rr], y0[rr], ssq0);
      ssum1 += y1[rr]; ssq1 = fmaf(y1[rr], y1[rr], ssq1);
      y2a[(size_t)(row0+rr)*128 + lane]      = __float2bfloat16(y0[rr]);
      y2a[(size_t)(row0+rr)*128 + 64 + lane] = __float2bfloat16(y1[rr]);
    }
  }
  red[wv][lane][0]=ssum0; red[wv][lane][1]=ssq0; red[wv][lane][2]=ssum1; red[wv][lane][3]=ssq1;
  __syncthreads();
  if (threadIdx.x < 64){
    float s0=0,q0=0,s1=0,q1=0;
#pragma unroll
    for (int v2=0; v2<4; ++v2){ s0+=red[v2][lane][0]; q0+=red[v2][lane][1]; s1+=red[v2][lane][2]; q1+=red[v2][lane][3]; }
    atomicAdd(&stats2a[lane], s0);      atomicAdd(&stats2a[128+lane], q0);
    atomicAdd(&stats2a[64+lane], s1);   atomicAdd(&stats2a[192+lane], q1);
  }
}

// ---- conv2b: 64x64 tiles, transposed activation staging, 4x4 thread tile ----
__global__ __launch_bounds__(256) void conv2b_kernel(
    const __hip_bfloat16* __restrict__ y2a, const float* __restrict__ stats2a,
    const float* __restrict__ g2a, const float* __restrict__ be2a,
    const float* __restrict__ W2b, const float* __restrict__ b2b,
    float* __restrict__ stats2b, unsigned* __restrict__ gmax, unsigned* __restrict__ gmin){
  __shared__ float Wl[128*64];
  __shared__ float aT[128*64];
  __shared__ float sc2a[128], sh2a[128];
  int tid = threadIdx.x;
  int ct = blockIdx.x & 3;
  int rb = blockIdx.x >> 2;                     // 0..511, 512 rows each
  int c0 = ct * 64;
  for (int t = tid; t < 128*64; t += 256){
    int kk = t >> 6, cc = t & 63;
    Wl[t] = W2b[kk*256 + c0 + cc];
  }
  if (tid < 128){
    const float inv = 1.0f / (float)RC2;
    float mu = stats2a[tid] * inv;
    float var = fmaxf(stats2a[128+tid]*inv - mu*mu, 0.f);
    float s = rsqrtf(var + 1e-5f) * g2a[tid];
    sc2a[tid] = s; sh2a[tid] = be2a[tid] - mu*s;
  }
  __syncthreads();
  int rg = tid & 15, cg = tid >> 4;
  float bb4[4];
#pragma unroll
  for (int j = 0; j < 4; ++j) bb4[j] = b2b[c0 + cg*4 + j];
  float vmn[4], vmx[4], ssum[4], ssq[4];
#pragma unroll
  for (int j = 0; j < 4; ++j){ vmn[j]=INFINITY; vmx[j]=-INFINITY; ssum[j]=0.f; ssq[j]=0.f; }
  int batch = rb >> 5;
  const unsigned short* y2u = (const unsigned short*)y2a;
  int srr = tid & 63, skq = tid >> 6;           // staging: row = srr, k-quarter = skq
  for (int tile = 0; tile < 8; ++tile){
    int row0 = rb*512 + tile*64;
    const unsigned short* src = y2u + (size_t)(row0 + srr)*128 + skq*32;
#pragma unroll
    for (int u = 0; u < 8; ++u){
      ushort4 v = *(const ushort4*)(src + u*4);
      int kk = skq*32 + u*4;
      float f0 = __uint_as_float((unsigned)v.x << 16);
      float f1 = __uint_as_float((unsigned)v.y << 16);
      float f2 = __uint_as_float((unsigned)v.z << 16);
      float f3 = __uint_as_float((unsigned)v.w << 16);
      aT[(kk+0)*64 + srr] = silu_f(fmaf(f0, sc2a[kk+0], sh2a[kk+0]));
      aT[(kk+1)*64 + srr] = silu_f(fmaf(f1, sc2a[kk+1], sh2a[kk+1]));
      aT[(kk+2)*64 + srr] = silu_f(fmaf(f2, sc2a[kk+2], sh2a[kk+2]));
      aT[(kk+3)*64 + srr] = silu_f(fmaf(f3, sc2a[kk+3], sh2a[kk+3]));
    }
    __syncthreads();
    float acc[4][4];
#pragma unroll
    for (int i = 0; i < 4; ++i)
#pragma unroll
      for (int j = 0; j < 4; ++j) acc[i][j] = 0.f;
#pragma unroll 4
    for (int kk = 0; kk < 128; ++kk){
      float4 av = *(const float4*)&aT[kk*64 + rg*4];
      float4 wv4 = *(const float4*)&Wl[kk*64 + cg*4];
      acc[0][0]=fmaf(av.x,wv4.x,acc[0][0]); acc[0][1]=fmaf(av.x,wv4.y,acc[0][1]);
      acc[0][2]=fmaf(av.x,wv4.z,acc[0][2]); acc[0][3]=fmaf(av.x,wv4.w,acc[0][3]);
      acc[1][0]=fmaf(av.y,wv4.x,acc[1][0]); acc[1][1]=fmaf(av.y,wv4.y,acc[1][1]);
      acc[1][2]=fmaf(av.y,wv4.z,acc[1][2]); acc[1][3]=fmaf(av.y,wv4.w,acc[1][3]);
      acc[2][0]=fmaf(av.z,wv4.x,acc[2][0]); acc[2][1]=fmaf(av.z,wv4.y,acc[2][1]);
      acc[2][2]=fmaf(av.z,wv4.z,acc[2][2]); acc[2][3]=fmaf(av.z,wv4.w,acc[2][3]);
      acc[3][0]=fmaf(av.w,wv4.x,acc[3][0]); acc[3][1]=fmaf(av.w,wv4.y,acc[3][1]);
      acc[3][2]=fmaf(av.w,wv4.z,acc[3][2]); acc[3][3]=fmaf(av.w,wv4.w,acc[3][3]);
    }
    __syncthreads();
#pragma unroll
    for (int i = 0; i < 4; ++i)
#pragma unroll
      for (int j = 0; j < 4; ++j){
        float y = acc[i][j] + bb4[j];
        vmn[j] = fminf(vmn[j], y); vmx[j] = fmaxf(vmx[j], y);
        ssum[j] += y; ssq[j] = fmaf(y, y, ssq[j]);
      }
  }
  float* scr = aT;   // 8192 floats scratch
#pragma unroll
  for (int j = 0; j < 4; ++j){
    scr[((0*16+rg)*16+cg)*4 + j] = vmn[j];
    scr[((1*16+rg)*16+cg)*4 + j] = vmx[j];
    scr[((2*16+rg)*16+cg)*4 + j] = ssum[j];
    scr[((3*16+rg)*16+cg)*4 + j] = ssq[j];
  }
  __syncthreads();
  if (tid < 64){
    int cg_ = tid >> 2, j_ = tid & 3;
    float mn = INFINITY, mx = -INFINITY, s = 0.f, q = 0.f;
    for (int r = 0; r < 16; ++r){
      mn = fminf(mn, scr[((0*16+r)*16+cg_)*4 + j_]);
      mx = fmaxf(mx, scr[((1*16+r)*16+cg_)*4 + j_]);
      s += scr[((2*16+r)*16+cg_)*4 + j_];
      q += scr[((3*16+r)*16+cg_)*4 + j_];
    }
    int c = c0 + cg_*4 + j_;
    atomicAdd(&stats2b[c], s);
    atomicAdd(&stats2b[256+c], q);
    atomicMaxF(&gmax[batch*256 + c], mx);
    atomicMinF(&gmin[batch*256 + c], mn);
  }
}

__global__ __launch_bounds__(256) void final_kernel(
    const float* __restrict__ stats2b, const unsigned* __restrict__ gmax,
    const unsigned* __restrict__ gmin, const float* __restrict__ g2b,
    const float* __restrict__ be2b, float* __restrict__ out){
  int t = blockIdx.x*256 + threadIdx.x;
  if (t >= NB*256) return;
  int c = t & 255;
  const float inv = 1.0f / (float)RC2;
  float mu = stats2b[c]*inv;
  float var = fmaxf(stats2b[256+c]*inv - mu*mu, 0.f);
  float sc = rsqrtf(var + 1e-5f)*g2b[c];
  float sh = be2b[c] - mu*sc;
  float mx = __uint_as_float(gmax[t]);
  float mn = __uint_as_float(gmin[t]);
  out[t] = fmaxf(silu_f(fmaf(mx, sc, sh)), silu_f(fmaf(mn, sc, sh)));
}

extern "C" void kernel_launch(void* const* d_in, const int* in_sizes, int n_in,
                              void* d_out, int out_size, void* d_ws, size_t ws_size,
                              hipStream_t stream){
  (void)in_sizes; (void)n_in; (void)out_size; (void)ws_size;
  const float* pos  = (const float*)d_in[0];
  const float* W1   = (const float*)d_in[1];
  const float* b1   = (const float*)d_in[2];
  const float* g1   = (const float*)d_in[3];
  const float* be1  = (const float*)d_in[4];
  const float* W2a  = (const float*)d_in[5];
  const float* b2a  = (const float*)d_in[6];
  const float* g2a  = (const float*)d_in[7];
  const float* be2a = (const float*)d_in[8];
  const float* W2b  = (const float*)d_in[9];
  const float* b2b  = (const float*)d_in[10];
  const float* g2b  = (const float*)d_in[11];
  const float* be2b = (const float*)d_in[12];

  char* w = (char*)d_ws;
  size_t off = 0;
  auto carve = [&](size_t bytes)->void*{ void* p = w + off; off += (bytes + 255) & ~(size_t)255; return p; };
  int*      idx1    = (int*)carve((size_t)NB*NN*KNNK*4);      // 2 MB
  float*    h       = (float*)carve((size_t)NB*NN*64*4);      // 8 MB
  int*      idxf    = (int*)carve((size_t)NB*MM*4);
  float*    pos2    = (float*)carve((size_t)NB*MM*3*4);
  int*      idx2    = (int*)carve((size_t)NB*MM*KNNK*4);      // 1 MB
  float*    stats1  = (float*)carve(128*4);
  float*    stats2a = (float*)carve(256*4);
  float*    stats2b = (float*)carve(512*4);
  unsigned* gmax    = (unsigned*)carve(4096*4);
  unsigned* gmin    = (unsigned*)carve(4096*4);
  __hip_bfloat16* y2a = (__hip_bfloat16*)carve((size_t)RC2*128*2);  // 64 MB
  // pknn buffers live inside the y2a region (dead before conv2a writes y2a)
  u64* pknn1 = (u64*)y2a;                          // 8 MB  (dead after K1)
  u64* pknn2 = (u64*)((char*)y2a + (32u<<20));     // 8 MB  (dead after K2)

  init_kernel<<<dim3(16), dim3(256), 0, stream>>>(stats1, stats2a, stats2b, gmax, gmin);
  k0_fps_knn1<<<dim3(272), dim3(256), 0, stream>>>(pos, idxf, pos2, pknn1);
  k1_merge1_knn2<<<dim3(384), dim3(256), 0, stream>>>(pknn1, idx1, pos2, pknn2);
  k2_merge2_c1stats<<<dim3(1088), dim3(256), 0, stream>>>(pknn2, idx2, pos, idx1, W1, b1, stats1);
  conv1_apply_kernel<<<dim3(1024), dim3(256), 0, stream>>>(pos, idx1, W1, b1, g1, be1, stats1, h);
  conv2a_kernel<<<dim3(1024), dim3(256), 0, stream>>>(h, idxf, pos2, idx2, W2a, b2a, stats2a, y2a);
  conv2b_kernel<<<dim3(2048), dim3(256), 0, stream>>>(y2a, stats2a, g2a, be2a, W2b, b2b, stats2b, gmax, gmin);
  final_kernel<<<dim3(16), dim3(256), 0, stream>>>(stats2b, gmax, gmin, g2b, be2b, (float*)d_out);
}

// Round 5
// 1171.277 us; speedup vs baseline: 1.3458x; 1.3458x over previous
//
#include <hip/hip_runtime.h>
#include <hip/hip_bf16.h>

#define NB 16
#define NN 2048
#define KNNK 16
#define MM 1024
#define RC1 (NB*NN*KNNK)   // 524288 conv1 BN rows
#define RC2 (NB*MM*KNNK)   // 262144 conv2 BN rows

typedef unsigned long long u64;

__device__ __forceinline__ float frn_mul(float a, float b){ return __fmul_rn(a,b); }
__device__ __forceinline__ float frn_add(float a, float b){ return __fadd_rn(a,b); }
__device__ __forceinline__ float frn_sub(float a, float b){ return __fsub_rn(a,b); }
__device__ __forceinline__ float silu_f(float x){ return x / (1.0f + __expf(-x)); }
__device__ __forceinline__ u64 umax64(u64 a, u64 b){ return a > b ? a : b; }

__device__ __forceinline__ unsigned f32_sortable(float f){
  unsigned u = __float_as_uint(f);
  return u ^ ((unsigned)((int)u >> 31) | 0x80000000u);
}

__device__ __forceinline__ void atomicMaxF(unsigned* addr, float v){
  if (v >= 0.f) atomicMax((int*)addr, (int)__float_as_uint(v));
  else          atomicMin(addr, __float_as_uint(v));
}
__device__ __forceinline__ void atomicMinF(unsigned* addr, float v){
  if (v >= 0.f) atomicMin((int*)addr, (int)__float_as_uint(v));
  else          atomicMax(addr, __float_as_uint(v));
}

__global__ __launch_bounds__(256) void init_kernel(float* stats1, float* stats2a, float* stats2b,
                                                   unsigned* gmax, unsigned* gmin){
  int t = blockIdx.x*256 + threadIdx.x;
  if (t < 128) stats1[t] = 0.f;
  if (t < 256) stats2a[t] = 0.f;
  if (t < 512) stats2b[t] = 0.f;
  if (t < 4096){ gmax[t] = 0xFF800000u; gmin[t] = 0x7F800000u; }
}

// ---- knn chunk: 256 query threads vs CHUNK staged points; sorted u64 top-16 ----
template<int CHUNK>
__device__ __forceinline__ void knn_chunk_body(const float* __restrict__ pos_b, int qbase, int jbase,
                                               float4* sm, u64* __restrict__ out, int tid){
  for (int t = tid; t < CHUNK; t += 256){
    const float* p = pos_b + (size_t)(jbase + t)*3;
    float x = p[0], y = p[1], z = p[2];
    float n2 = frn_add(frn_add(frn_mul(x,x), frn_mul(y,y)), frn_mul(z,z));
    sm[t] = make_float4(x,y,z,n2);
  }
  __syncthreads();
  int i = qbase + tid;
  const float* qp = pos_b + (size_t)i*3;
  float xi = qp[0], yi = qp[1], zi = qp[2];
  float n2i = frn_add(frn_add(frn_mul(xi,xi), frn_mul(yi,yi)), frn_mul(zi,zi));
  u64 best[KNNK];
#pragma unroll
  for (int p = 0; p < KNNK; ++p) best[p] = ~0ull;
  for (int jj = 0; jj < CHUNK; ++jj){
    float4 v = sm[jj];
    float e = frn_add(frn_add(frn_mul(xi,v.x), frn_mul(yi,v.y)), frn_mul(zi,v.z));
    float d = frn_sub(frn_add(n2i, v.w), frn_mul(2.0f, e));
    u64 key = ((u64)f32_sortable(d) << 32) | (unsigned)(jbase + jj);
    if (key < best[KNNK-1]){
      u64 cur = key;
#pragma unroll
      for (int p = 0; p < KNNK; ++p){
        u64 mn = best[p] < cur ? best[p] : cur;
        u64 mx = best[p] < cur ? cur : best[p];
        best[p] = mn; cur = mx;
      }
    }
  }
#pragma unroll
  for (int p = 0; p < KNNK; ++p) out[p] = best[p];
}

// ---- K0: blocks 0..15 = FPS (reg points, tree argmax, u64-only DPP reduce,
//          coords via one broadcast LDS read), blocks 16..271 = knn1 chunks ----
__global__ __launch_bounds__(256) void k0_fps_knn1(const float* __restrict__ pos,
    int* __restrict__ idxf, float* __restrict__ pos2, u64* __restrict__ pknn1){
  __shared__ __align__(16) char smem[32*1024 + 64];
  int tid = threadIdx.x;
  if (blockIdx.x < 16){
    int b = blockIdx.x;
    float4* pts4 = (float4*)smem;          // 2048 * 16B = 32 KB
    u64* wred = (u64*)(smem + 32*1024);    // [2][4]
    const float* pb = pos + (size_t)b*NN*3;
    float X[8], Y[8], Z[8], MD[8];
    unsigned LO[8];
#pragma unroll
    for (int q = 0; q < 8; ++q){
      int p = tid + 256*q;
      float x = pb[p*3+0], y = pb[p*3+1], z = pb[p*3+2];
      X[q] = x; Y[q] = y; Z[q] = z;
      LO[q] = ~(unsigned)p;
      pts4[p] = make_float4(x, y, z, 0.f);
    }
    float qx = pb[0], qy = pb[1], qz = pb[2];
#pragma unroll
    for (int q = 0; q < 8; ++q){
      float dx = frn_sub(X[q],qx), dy = frn_sub(Y[q],qy), dz = frn_sub(Z[q],qz);
      MD[q] = frn_add(frn_add(frn_mul(dx,dx), frn_mul(dy,dy)), frn_mul(dz,dz));
    }
    if (tid == 0){
      idxf[b*MM + 0] = 0;
      pos2[(size_t)(b*MM)*3+0] = qx;
      pos2[(size_t)(b*MM)*3+1] = qy;
      pos2[(size_t)(b*MM)*3+2] = qz;
    }
    int wv = tid >> 6;
    __syncthreads();
    for (int s = 1; s < MM; ++s){
      // lane-local TREE max over 8 u64 keys (depth 3)
      u64 t0 = umax64(((u64)__float_as_uint(MD[0])<<32)|LO[0], ((u64)__float_as_uint(MD[1])<<32)|LO[1]);
      u64 t1 = umax64(((u64)__float_as_uint(MD[2])<<32)|LO[2], ((u64)__float_as_uint(MD[3])<<32)|LO[3]);
      u64 t2 = umax64(((u64)__float_as_uint(MD[4])<<32)|LO[4], ((u64)__float_as_uint(MD[5])<<32)|LO[5]);
      u64 t3 = umax64(((u64)__float_as_uint(MD[6])<<32)|LO[6], ((u64)__float_as_uint(MD[7])<<32)|LO[7]);
      u64 kk = umax64(umax64(t0, t1), umax64(t2, t3));
      // in-wave max reduce on the u64 key only
#define RED_DPP(CTRL) { \
      unsigned lo_ = (unsigned)kk, hi_ = (unsigned)(kk>>32); \
      unsigned plo = (unsigned)__builtin_amdgcn_update_dpp((int)lo_,(int)lo_,CTRL,0xF,0xF,false); \
      unsigned phi = (unsigned)__builtin_amdgcn_update_dpp((int)hi_,(int)hi_,CTRL,0xF,0xF,false); \
      u64 o = ((u64)phi<<32)|plo; kk = o > kk ? o : kk; }
      RED_DPP(0xB1)   // quad_perm [1,0,3,2] : xor1
      RED_DPP(0x4E)   // quad_perm [2,3,0,1] : xor2
      RED_DPP(0x124)  // row_ror:4
      RED_DPP(0x128)  // row_ror:8
#undef RED_DPP
      {
        unsigned lo_ = (unsigned)kk, hi_ = (unsigned)(kk>>32);
        unsigned plo = (unsigned)__builtin_amdgcn_ds_swizzle((int)lo_, 0x401F);
        unsigned phi = (unsigned)__builtin_amdgcn_ds_swizzle((int)hi_, 0x401F);
        u64 o = ((u64)phi<<32)|plo; kk = o > kk ? o : kk;
      }
      {
        unsigned lo_ = (unsigned)kk, hi_ = (unsigned)(kk>>32);
        unsigned plo = (unsigned)__shfl_xor((int)lo_, 32);
        unsigned phi = (unsigned)__shfl_xor((int)hi_, 32);
        u64 o = ((u64)phi<<32)|plo; kk = o > kk ? o : kk;
      }
      // cross-wave: one b64 write per wave leader, single barrier (parity slots)
      int par = s & 1;
      if ((tid & 63) == 0) wred[par*4 + wv] = kk;
      __syncthreads();
      const u64* wr = wred + par*4;
      u64 K = umax64(umax64(wr[0], wr[1]), umax64(wr[2], wr[3]));
      unsigned wp = ~(unsigned)K;
      float4 wc = pts4[wp];                 // broadcast ds_read_b128
      if (tid == 0){
        idxf[b*MM + s] = (int)wp;
        pos2[(size_t)(b*MM+s)*3+0] = wc.x;
        pos2[(size_t)(b*MM+s)*3+1] = wc.y;
        pos2[(size_t)(b*MM+s)*3+2] = wc.z;
      }
#pragma unroll
      for (int q = 0; q < 8; ++q){
        float dx = frn_sub(X[q],wc.x), dy = frn_sub(Y[q],wc.y), dz = frn_sub(Z[q],wc.z);
        float d = frn_add(frn_add(frn_mul(dx,dx), frn_mul(dy,dy)), frn_mul(dz,dz));
        MD[q] = fminf(MD[q], d);
      }
    }
  } else {
    int cid = blockIdx.x - 16;          // 0..255
    int b = cid >> 4;
    int rblk = (cid >> 1) & 7;
    int ch = cid & 1;
    float4* sm = (float4*)smem;         // 1024 * 16B
    const float* pos_b = pos + (size_t)b*NN*3;
    int i = rblk*256 + tid;
    u64* out = pknn1 + ((size_t)(b*NN + i)*2 + ch)*KNNK;
    knn_chunk_body<1024>(pos_b, rblk*256, ch*1024, sm, out, tid);
  }
}

// ---- K1: blocks 0..127 = merge1 (2-way), blocks 128..383 = knn2 chunks ----
__global__ __launch_bounds__(256) void k1_merge1_knn2(const u64* __restrict__ pknn1,
    int* __restrict__ idx1, const float* __restrict__ pos2, u64* __restrict__ pknn2){
  __shared__ __align__(16) float4 sm[256];
  int tid = threadIdx.x;
  if (blockIdx.x < 128){
    int row = blockIdx.x*256 + tid;     // 32768 rows
    const u64* A = pknn1 + (size_t)row*32;
    const u64* B = A + 16;
    int ia = 0, ib = 0;
    int* op = idx1 + (size_t)row*KNNK;
#pragma unroll
    for (int p = 0; p < KNNK; ++p){
      u64 ka = A[ia], kb = B[ib];
      if (ka < kb){ op[p] = (int)(unsigned)ka; ++ia; }
      else        { op[p] = (int)(unsigned)kb; ++ib; }
    }
  } else {
    int cid = blockIdx.x - 128;         // 0..255
    int b = cid >> 4;
    int rblk = (cid >> 2) & 3;
    int ch = cid & 3;
    const float* pos_b = pos2 + (size_t)b*MM*3;
    int i = rblk*256 + tid;
    u64* out = pknn2 + ((size_t)(b*MM + i)*4 + ch)*KNNK;
    knn_chunk_body<256>(pos_b, rblk*256, ch*256, sm, out, tid);
  }
}

// ---- K2: blocks 0..63 = merge2 (4-way), blocks 64..1087 = conv1 stats ----
__global__ __launch_bounds__(256) void k2_merge2_c1stats(const u64* __restrict__ pknn2,
    int* __restrict__ idx2, const float* __restrict__ pos, const int* __restrict__ idx1,
    const float* __restrict__ W1, const float* __restrict__ b1, float* __restrict__ stats1){
  __shared__ float red[4][64][2];
  int tid = threadIdx.x;
  if (blockIdx.x < 64){
    int row = blockIdx.x*256 + tid;     // 16384 rows
    const u64* L = pknn2 + (size_t)row*64;
    int o0=0, o1=0, o2=0, o3=0;
    int* op = idx2 + (size_t)row*KNNK;
#pragma unroll
    for (int p = 0; p < KNNK; ++p){
      u64 k0 = L[o0], k1 = L[16+o1], k2 = L[32+o2], k3 = L[48+o3];
      u64 m01 = k0 < k1 ? k0 : k1;
      u64 m23 = k2 < k3 ? k2 : k3;
      u64 m = m01 < m23 ? m01 : m23;
      op[p] = (int)(unsigned)m;
      o0 += (m == k0); o1 += (m == k1); o2 += (m == k2); o3 += (m == k3);
    }
    return;
  }
  int lane = tid & 63, wv = tid >> 6;
  int wave = (blockIdx.x - 64)*4 + wv;  // 0..4095, 8 rows each
  float w[6];
#pragma unroll
  for (int f = 0; f < 6; ++f) w[f] = W1[f*64 + lane];
  float bias = b1[lane];
  float ssum = 0.f, ssq = 0.f;
  for (int r = 0; r < 8; ++r){
    int row = wave*8 + r;
    int b = row >> 11, ii = row & 2047;
    const float* pi = pos + ((size_t)(b*NN + ii))*3;
    float xi = pi[0], yi = pi[1], zi = pi[2];
    const int* ip = idx1 + (size_t)row * KNNK;
#pragma unroll 4
    for (int k = 0; k < KNNK; ++k){
      int j = ip[k];
      const float* pj = pos + ((size_t)(b*NN + j))*3;
      float xj = pj[0], yj = pj[1], zj = pj[2];
      float y = bias;
      y = fmaf(xj, w[0], y); y = fmaf(yj, w[1], y); y = fmaf(zj, w[2], y);
      y = fmaf(xj - xi, w[3], y); y = fmaf(yj - yi, w[4], y); y = fmaf(zj - zi, w[5], y);
      ssum += y; ssq = fmaf(y, y, ssq);
    }
  }
  red[wv][lane][0] = ssum; red[wv][lane][1] = ssq;
  __syncthreads();
  if (tid < 64){
    float s = red[0][lane][0]+red[1][lane][0]+red[2][lane][0]+red[3][lane][0];
    float q = red[0][lane][1]+red[1][lane][1]+red[2][lane][1]+red[3][lane][1];
    atomicAdd(&stats1[lane], s);
    atomicAdd(&stats1[64+lane], q);
  }
}

__global__ __launch_bounds__(256) void conv1_apply_kernel(
    const float* __restrict__ pos, const int* __restrict__ idx1,
    const float* __restrict__ W1, const float* __restrict__ b1,
    const float* __restrict__ g1, const float* __restrict__ be1,
    const float* __restrict__ stats1, float* __restrict__ h){
  int lane = threadIdx.x & 63, wv = threadIdx.x >> 6;
  int wave = blockIdx.x*4 + wv;
  float w[6];
#pragma unroll
  for (int f = 0; f < 6; ++f) w[f] = W1[f*64 + lane];
  float bias = b1[lane];
  const float inv = 1.0f / (float)RC1;
  float mu = stats1[lane] * inv;
  float var = fmaxf(stats1[64+lane]*inv - mu*mu, 0.f);
  float sc = rsqrtf(var + 1e-5f) * g1[lane];
  float sh = be1[lane] - mu*sc;
  for (int r = 0; r < 8; ++r){
    int row = wave*8 + r;
    int b = row >> 11, ii = row & 2047;
    const float* pi = pos + ((size_t)(b*NN + ii))*3;
    float xi = pi[0], yi = pi[1], zi = pi[2];
    const int* ip = idx1 + (size_t)row * KNNK;
    float ymn = INFINITY, ymx = -INFINITY;
#pragma unroll 4
    for (int k = 0; k < KNNK; ++k){
      int j = ip[k];
      const float* pj = pos + ((size_t)(b*NN + j))*3;
      float xj = pj[0], yj = pj[1], zj = pj[2];
      float y = bias;
      y = fmaf(xj, w[0], y); y = fmaf(yj, w[1], y); y = fmaf(zj, w[2], y);
      y = fmaf(xj - xi, w[3], y); y = fmaf(yj - yi, w[4], y); y = fmaf(zj - zi, w[5], y);
      ymn = fminf(ymn, y); ymx = fmaxf(ymx, y);
    }
    h[((size_t)row << 6) + lane] = fmaxf(silu_f(fmaf(ymx, sc, sh)), silu_f(fmaf(ymn, sc, sh)));
  }
}

// ---- conv2a: 4 rows share each LDS weight read; double indirection replaces hs ----
__global__ __launch_bounds__(256) void conv2a_kernel(
    const float* __restrict__ h, const int* __restrict__ idxf,
    const float* __restrict__ pos2, const int* __restrict__ idx2,
    const float* __restrict__ W2a, const float* __restrict__ b2a,
    float* __restrict__ stats2a, __hip_bfloat16* __restrict__ y2a){
  __shared__ float Wl[67*128];
  __shared__ float red[4][64][4];
  for (int t = threadIdx.x; t < 67*128; t += 256) Wl[t] = W2a[t];
  __syncthreads();
  int lane = threadIdx.x & 63, wv = threadIdx.x >> 6;
  int wave = blockIdx.x*4 + wv;                 // 0..4095, 64 rows each
  float bias0 = b2a[lane], bias1 = b2a[64+lane];
  float ssum0=0, ssq0=0, ssum1=0, ssq1=0;
  for (int r4 = 0; r4 < 16; ++r4){
    int row0 = wave*64 + r4*4;
    int b = row0 >> 14;
    int m = (row0 >> 4) & 1023;
    int j0 = idx2[row0+0], j1 = idx2[row0+1], j2 = idx2[row0+2], j3 = idx2[row0+3];
    int q0 = idxf[b*MM + j0], q1 = idxf[b*MM + j1], q2 = idxf[b*MM + j2], q3 = idxf[b*MM + j3];
    const float4* h0 = (const float4*)(h + ((size_t)(b*NN + q0) << 6));
    const float4* h1 = (const float4*)(h + ((size_t)(b*NN + q1) << 6));
    const float4* h2 = (const float4*)(h + ((size_t)(b*NN + q2) << 6));
    const float4* h3 = (const float4*)(h + ((size_t)(b*NN + q3) << 6));
    float y00=bias0, y01=bias1, y10=bias0, y11=bias1;
    float y20=bias0, y21=bias1, y30=bias0, y31=bias1;
#define C2A_STEP(e, a0v, a1v, a2v, a3v) { \
      float w0_ = Wl[(e)*128 + lane], w1_ = Wl[(e)*128 + 64 + lane]; \
      y00 = fmaf(a0v, w0_, y00); y01 = fmaf(a0v, w1_, y01); \
      y10 = fmaf(a1v, w0_, y10); y11 = fmaf(a1v, w1_, y11); \
      y20 = fmaf(a2v, w0_, y20); y21 = fmaf(a2v, w1_, y21); \
      y30 = fmaf(a3v, w0_, y30); y31 = fmaf(a3v, w1_, y31); }
#pragma unroll
    for (int f4 = 0; f4 < 16; ++f4){
      float4 v0 = h0[f4], v1 = h1[f4], v2 = h2[f4], v3 = h3[f4];
      C2A_STEP(f4*4+0, v0.x, v1.x, v2.x, v3.x)
      C2A_STEP(f4*4+1, v0.y, v1.y, v2.y, v3.y)
      C2A_STEP(f4*4+2, v0.z, v1.z, v2.z, v3.z)
      C2A_STEP(f4*4+3, v0.w, v1.w, v2.w, v3.w)
    }
    const float* pm = pos2 + ((size_t)(b*MM + m))*3;
    float pmx = pm[0], pmy = pm[1], pmz = pm[2];
    const float* pj0 = pos2 + ((size_t)(b*MM + j0))*3;
    const float* pj1 = pos2 + ((size_t)(b*MM + j1))*3;
    const float* pj2 = pos2 + ((size_t)(b*MM + j2))*3;
    const float* pj3 = pos2 + ((size_t)(b*MM + j3))*3;
    C2A_STEP(64, pj0[0]-pmx, pj1[0]-pmx, pj2[0]-pmx, pj3[0]-pmx)
    C2A_STEP(65, pj0[1]-pmy, pj1[1]-pmy, pj2[1]-pmy, pj3[1]-pmy)
    C2A_STEP(66, pj0[2]-pmz, pj1[2]-pmz, pj2[2]-pmz, pj3[2]-pmz)
#undef C2A_STEP
    ssum0 += y00+y10+y20+y30;
    ssum1 += y01+y11+y21+y31;
    ssq0 = fmaf(y00,y00,fmaf(y10,y10,fmaf(y20,y20,fmaf(y30,y30,ssq0))));
    ssq1 = fmaf(y01,y01,fmaf(y11,y11,fmaf(y21,y21,fmaf(y31,y31,ssq1))));
    y2a[(size_t)(row0+0)*128 + lane]      = __float2bfloat16(y00);
    y2a[(size_t)(row0+0)*128 + 64 + lane] = __float2bfloat16(y01);
    y2a[(size_t)(row0+1)*128 + lane]      = __float2bfloat16(y10);
    y2a[(size_t)(row0+1)*128 + 64 + lane] = __float2bfloat16(y11);
    y2a[(size_t)(row0+2)*128 + lane]      = __float2bfloat16(y20);
    y2a[(size_t)(row0+2)*128 + 64 + lane] = __float2bfloat16(y21);
    y2a[(size_t)(row0+3)*128 + lane]      = __float2bfloat16(y30);
    y2a[(size_t)(row0+3)*128 + 64 + lane] = __float2bfloat16(y31);
  }
  red[wv][lane][0]=ssum0; red[wv][lane][1]=ssq0; red[wv][lane][2]=ssum1; red[wv][lane][3]=ssq1;
  __syncthreads();
  if (threadIdx.x < 64){
    float s0=0,q0=0,s1=0,q1=0;
#pragma unroll
    for (int v2=0; v2<4; ++v2){ s0+=red[v2][lane][0]; q0+=red[v2][lane][1]; s1+=red[v2][lane][2]; q1+=red[v2][lane][3]; }
    atomicAdd(&stats2a[lane], s0);      atomicAdd(&stats2a[128+lane], q0);
    atomicAdd(&stats2a[64+lane], s1);   atomicAdd(&stats2a[192+lane], q1);
  }
}

// ---- conv2b: 64x64 tiles, transposed activation staging, 4x4 thread tile ----
__global__ __launch_bounds__(256) void conv2b_kernel(
    const __hip_bfloat16* __restrict__ y2a, const float* __restrict__ stats2a,
    const float* __restrict__ g2a, const float* __restrict__ be2a,
    const float* __restrict__ W2b, const float* __restrict__ b2b,
    float* __restrict__ stats2b, unsigned* __restrict__ gmax, unsigned* __restrict__ gmin){
  __shared__ float Wl[128*64];
  __shared__ float aT[128*64];
  __shared__ float sc2a[128], sh2a[128];
  int tid = threadIdx.x;
  int ct = blockIdx.x & 3;
  int rb = blockIdx.x >> 2;                     // 0..511, 512 rows each
  int c0 = ct * 64;
  for (int t = tid; t < 128*64; t += 256){
    int kk = t >> 6, cc = t & 63;
    Wl[t] = W2b[kk*256 + c0 + cc];
  }
  if (tid < 128){
    const float inv = 1.0f / (float)RC2;
    float mu = stats2a[tid] * inv;
    float var = fmaxf(stats2a[128+tid]*inv - mu*mu, 0.f);
    float s = rsqrtf(var + 1e-5f) * g2a[tid];
    sc2a[tid] = s; sh2a[tid] = be2a[tid] - mu*s;
  }
  __syncthreads();
  int rg = tid & 15, cg = tid >> 4;
  float bb4[4];
#pragma unroll
  for (int j = 0; j < 4; ++j) bb4[j] = b2b[c0 + cg*4 + j];
  float vmn[4], vmx[4], ssum[4], ssq[4];
#pragma unroll
  for (int j = 0; j < 4; ++j){ vmn[j]=INFINITY; vmx[j]=-INFINITY; ssum[j]=0.f; ssq[j]=0.f; }
  int batch = rb >> 5;
  const unsigned short* y2u = (const unsigned short*)y2a;
  int srr = tid & 63, skq = tid >> 6;           // staging: row = srr, k-quarter = skq
  for (int tile = 0; tile < 8; ++tile){
    int row0 = rb*512 + tile*64;
    const unsigned short* src = y2u + (size_t)(row0 + srr)*128 + skq*32;
#pragma unroll
    for (int u = 0; u < 8; ++u){
      ushort4 v = *(const ushort4*)(src + u*4);
      int kk = skq*32 + u*4;
      float f0 = __uint_as_float((unsigned)v.x << 16);
      float f1 = __uint_as_float((unsigned)v.y << 16);
      float f2 = __uint_as_float((unsigned)v.z << 16);
      float f3 = __uint_as_float((unsigned)v.w << 16);
      aT[(kk+0)*64 + srr] = silu_f(fmaf(f0, sc2a[kk+0], sh2a[kk+0]));
      aT[(kk+1)*64 + srr] = silu_f(fmaf(f1, sc2a[kk+1], sh2a[kk+1]));
      aT[(kk+2)*64 + srr] = silu_f(fmaf(f2, sc2a[kk+2], sh2a[kk+2]));
      aT[(kk+3)*64 + srr] = silu_f(fmaf(f3, sc2a[kk+3], sh2a[kk+3]));
    }
    __syncthreads();
    float acc[4][4];
#pragma unroll
    for (int i = 0; i < 4; ++i)
#pragma unroll
      for (int j = 0; j < 4; ++j) acc[i][j] = 0.f;
#pragma unroll 4
    for (int kk = 0; kk < 128; ++kk){
      float4 av = *(const float4*)&aT[kk*64 + rg*4];
      float4 wv4 = *(const float4*)&Wl[kk*64 + cg*4];
      acc[0][0]=fmaf(av.x,wv4.x,acc[0][0]); acc[0][1]=fmaf(av.x,wv4.y,acc[0][1]);
      acc[0][2]=fmaf(av.x,wv4.z,acc[0][2]); acc[0][3]=fmaf(av.x,wv4.w,acc[0][3]);
      acc[1][0]=fmaf(av.y,wv4.x,acc[1][0]); acc[1][1]=fmaf(av.y,wv4.y,acc[1][1]);
      acc[1][2]=fmaf(av.y,wv4.z,acc[1][2]); acc[1][3]=fmaf(av.y,wv4.w,acc[1][3]);
      acc[2][0]=fmaf(av.z,wv4.x,acc[2][0]); acc[2][1]=fmaf(av.z,wv4.y,acc[2][1]);
      acc[2][2]=fmaf(av.z,wv4.z,acc[2][2]); acc[2][3]=fmaf(av.z,wv4.w,acc[2][3]);
      acc[3][0]=fmaf(av.w,wv4.x,acc[3][0]); acc[3][1]=fmaf(av.w,wv4.y,acc[3][1]);
      acc[3][2]=fmaf(av.w,wv4.z,acc[3][2]); acc[3][3]=fmaf(av.w,wv4.w,acc[3][3]);
    }
    __syncthreads();
#pragma unroll
    for (int i = 0; i < 4; ++i)
#pragma unroll
      for (int j = 0; j < 4; ++j){
        float y = acc[i][j] + bb4[j];
        vmn[j] = fminf(vmn[j], y); vmx[j] = fmaxf(vmx[j], y);
        ssum[j] += y; ssq[j] = fmaf(y, y, ssq[j]);
      }
  }
  float* scr = aT;   // 8192 floats scratch
#pragma unroll
  for (int j = 0; j < 4; ++j){
    scr[((0*16+rg)*16+cg)*4 + j] = vmn[j];
    scr[((1*16+rg)*16+cg)*4 + j] = vmx[j];
    scr[((2*16+rg)*16+cg)*4 + j] = ssum[j];
    scr[((3*16+rg)*16+cg)*4 + j] = ssq[j];
  }
  __syncthreads();
  if (tid < 64){
    int cg_ = tid >> 2, j_ = tid & 3;
    float mn = INFINITY, mx = -INFINITY, s = 0.f, q = 0.f;
    for (int r = 0; r < 16; ++r){
      mn = fminf(mn, scr[((0*16+r)*16+cg_)*4 + j_]);
      mx = fmaxf(mx, scr[((1*16+r)*16+cg_)*4 + j_]);
      s += scr[((2*16+r)*16+cg_)*4 + j_];
      q += scr[((3*16+r)*16+cg_)*4 + j_];
    }
    int c = c0 + cg_*4 + j_;
    atomicAdd(&stats2b[c], s);
    atomicAdd(&stats2b[256+c], q);
    atomicMaxF(&gmax[batch*256 + c], mx);
    atomicMinF(&gmin[batch*256 + c], mn);
  }
}

__global__ __launch_bounds__(256) void final_kernel(
    const float* __restrict__ stats2b, const unsigned* __restrict__ gmax,
    const unsigned* __restrict__ gmin, const float* __restrict__ g2b,
    const float* __restrict__ be2b, float* __restrict__ out){
  int t = blockIdx.x*256 + threadIdx.x;
  if (t >= NB*256) return;
  int c = t & 255;
  const float inv = 1.0f / (float)RC2;
  float mu = stats2b[c]*inv;
  float var = fmaxf(stats2b[256+c]*inv - mu*mu, 0.f);
  float sc = rsqrtf(var + 1e-5f)*g2b[c];
  float sh = be2b[c] - mu*sc;
  float mx = __uint_as_float(gmax[t]);
  float mn = __uint_as_float(gmin[t]);
  out[t] = fmaxf(silu_f(fmaf(mx, sc, sh)), silu_f(fmaf(mn, sc, sh)));
}

extern "C" void kernel_launch(void* const* d_in, const int* in_sizes, int n_in,
                              void* d_out, int out_size, void* d_ws, size_t ws_size,
                              hipStream_t stream){
  (void)in_sizes; (void)n_in; (void)out_size; (void)ws_size;
  const float* pos  = (const float*)d_in[0];
  const float* W1   = (const float*)d_in[1];
  const float* b1   = (const float*)d_in[2];
  const float* g1   = (const float*)d_in[3];
  const float* be1  = (const float*)d_in[4];
  const float* W2a  = (const float*)d_in[5];
  const float* b2a  = (const float*)d_in[6];
  const float* g2a  = (const float*)d_in[7];
  const float* be2a = (const float*)d_in[8];
  const float* W2b  = (const float*)d_in[9];
  const float* b2b  = (const float*)d_in[10];
  const float* g2b  = (const float*)d_in[11];
  const float* be2b = (const float*)d_in[12];

  char* w = (char*)d_ws;
  size_t off = 0;
  auto carve = [&](size_t bytes)->void*{ void* p = w + off; off += (bytes + 255) & ~(size_t)255; return p; };
  int*      idx1    = (int*)carve((size_t)NB*NN*KNNK*4);      // 2 MB
  float*    h       = (float*)carve((size_t)NB*NN*64*4);      // 8 MB
  int*      idxf    = (int*)carve((size_t)NB*MM*4);
  float*    pos2    = (float*)carve((size_t)NB*MM*3*4);
  int*      idx2    = (int*)carve((size_t)NB*MM*KNNK*4);      // 1 MB
  float*    stats1  = (float*)carve(128*4);
  float*    stats2a = (float*)carve(256*4);
  float*    stats2b = (float*)carve(512*4);
  unsigned* gmax    = (unsigned*)carve(4096*4);
  unsigned* gmin    = (unsigned*)carve(4096*4);
  __hip_bfloat16* y2a = (__hip_bfloat16*)carve((size_t)RC2*128*2);  // 64 MB
  // pknn buffers live inside the y2a region (dead before conv2a writes y2a)
  u64* pknn1 = (u64*)y2a;                          // 8 MB  (dead after K1)
  u64* pknn2 = (u64*)((char*)y2a + (32u<<20));     // 8 MB  (dead after K2)

  init_kernel<<<dim3(16), dim3(256), 0, stream>>>(stats1, stats2a, stats2b, gmax, gmin);
  k0_fps_knn1<<<dim3(272), dim3(256), 0, stream>>>(pos, idxf, pos2, pknn1);
  k1_merge1_knn2<<<dim3(384), dim3(256), 0, stream>>>(pknn1, idx1, pos2, pknn2);
  k2_merge2_c1stats<<<dim3(1088), dim3(256), 0, stream>>>(pknn2, idx2, pos, idx1, W1, b1, stats1);
  conv1_apply_kernel<<<dim3(1024), dim3(256), 0, stream>>>(pos, idx1, W1, b1, g1, be1, stats1, h);
  conv2a_kernel<<<dim3(1024), dim3(256), 0, stream>>>(h, idxf, pos2, idx2, W2a, b2a, stats2a, y2a);
  conv2b_kernel<<<dim3(2048), dim3(256), 0, stream>>>(y2a, stats2a, g2a, be2a, W2b, b2b, stats2b, gmax, gmin);
  final_kernel<<<dim3(16), dim3(256), 0, stream>>>(stats2b, gmax, gmin, g2b, be2b, (float*)d_out);
}

// Round 6
// 1165.751 us; speedup vs baseline: 1.3522x; 1.0047x over previous
//
#include <hip/hip_runtime.h>
#include <hip/hip_bf16.h>

#define NB 16
#define NN 2048
#define KNNK 16
#define MM 1024
#define RC1 (NB*NN*KNNK)   // 524288 conv1 BN rows
#define RC2 (NB*MM*KNNK)   // 262144 conv2 BN rows

typedef unsigned long long u64;

__device__ __forceinline__ float frn_mul(float a, float b){ return __fmul_rn(a,b); }
__device__ __forceinline__ float frn_add(float a, float b){ return __fadd_rn(a,b); }
__device__ __forceinline__ float frn_sub(float a, float b){ return __fsub_rn(a,b); }
__device__ __forceinline__ float silu_f(float x){ return x / (1.0f + __expf(-x)); }
__device__ __forceinline__ u64 umax64(u64 a, u64 b){ return a > b ? a : b; }

__device__ __forceinline__ unsigned f32_sortable(float f){
  unsigned u = __float_as_uint(f);
  return u ^ ((unsigned)((int)u >> 31) | 0x80000000u);
}

__device__ __forceinline__ void atomicMaxF(unsigned* addr, float v){
  if (v >= 0.f) atomicMax((int*)addr, (int)__float_as_uint(v));
  else          atomicMin(addr, __float_as_uint(v));
}
__device__ __forceinline__ void atomicMinF(unsigned* addr, float v){
  if (v >= 0.f) atomicMin((int*)addr, (int)__float_as_uint(v));
  else          atomicMax(addr, __float_as_uint(v));
}

__global__ __launch_bounds__(256) void init_kernel(float* stats1, float* stats2a, float* stats2b,
                                                   unsigned* gmax, unsigned* gmin){
  int t = blockIdx.x*256 + threadIdx.x;
  if (t < 128) stats1[t] = 0.f;
  if (t < 256) stats2a[t] = 0.f;
  if (t < 512) stats2b[t] = 0.f;
  if (t < 4096){ gmax[t] = 0xFF800000u; gmin[t] = 0x7F800000u; }
}

// ---- knn chunk: 256 query threads vs CHUNK staged points; sorted u64 top-16 ----
template<int CHUNK>
__device__ __forceinline__ void knn_chunk_body(const float* __restrict__ pos_b, int qbase, int jbase,
                                               float4* sm, u64* __restrict__ out, int tid){
  for (int t = tid; t < CHUNK; t += 256){
    const float* p = pos_b + (size_t)(jbase + t)*3;
    float x = p[0], y = p[1], z = p[2];
    float n2 = frn_add(frn_add(frn_mul(x,x), frn_mul(y,y)), frn_mul(z,z));
    sm[t] = make_float4(x,y,z,n2);
  }
  __syncthreads();
  int i = qbase + tid;
  const float* qp = pos_b + (size_t)i*3;
  float xi = qp[0], yi = qp[1], zi = qp[2];
  float n2i = frn_add(frn_add(frn_mul(xi,xi), frn_mul(yi,yi)), frn_mul(zi,zi));
  u64 best[KNNK];
#pragma unroll
  for (int p = 0; p < KNNK; ++p) best[p] = ~0ull;
  for (int jj = 0; jj < CHUNK; ++jj){
    float4 v = sm[jj];
    float e = frn_add(frn_add(frn_mul(xi,v.x), frn_mul(yi,v.y)), frn_mul(zi,v.z));
    float d = frn_sub(frn_add(n2i, v.w), frn_mul(2.0f, e));
    u64 key = ((u64)f32_sortable(d) << 32) | (unsigned)(jbase + jj);
    if (key < best[KNNK-1]){
      u64 cur = key;
#pragma unroll
      for (int p = 0; p < KNNK; ++p){
        u64 mn = best[p] < cur ? best[p] : cur;
        u64 mx = best[p] < cur ? cur : best[p];
        best[p] = mn; cur = mx;
      }
    }
  }
#pragma unroll
  for (int p = 0; p < KNNK; ++p) out[p] = best[p];
}

// ---- K0: blocks 0..15 = FPS (reg points, all-DPP wave reduce incl. row_bcast,
//          coords via one broadcast LDS read), blocks 16..271 = knn1 chunks ----
__global__ __launch_bounds__(256) void k0_fps_knn1(const float* __restrict__ pos,
    int* __restrict__ idxf, float* __restrict__ pos2, u64* __restrict__ pknn1){
  __shared__ __align__(16) char smem[32*1024 + 64];
  int tid = threadIdx.x;
  if (blockIdx.x < 16){
    int b = blockIdx.x;
    float4* pts4 = (float4*)smem;          // 2048 * 16B = 32 KB
    u64* wred = (u64*)(smem + 32*1024);    // [2][4]
    const float* pb = pos + (size_t)b*NN*3;
    float X[8], Y[8], Z[8], MD[8];
    unsigned LO[8];
#pragma unroll
    for (int q = 0; q < 8; ++q){
      int p = tid + 256*q;
      float x = pb[p*3+0], y = pb[p*3+1], z = pb[p*3+2];
      X[q] = x; Y[q] = y; Z[q] = z;
      LO[q] = ~(unsigned)p;
      pts4[p] = make_float4(x, y, z, 0.f);
    }
    float qx = pb[0], qy = pb[1], qz = pb[2];
#pragma unroll
    for (int q = 0; q < 8; ++q){
      float dx = frn_sub(X[q],qx), dy = frn_sub(Y[q],qy), dz = frn_sub(Z[q],qz);
      MD[q] = frn_add(frn_add(frn_mul(dx,dx), frn_mul(dy,dy)), frn_mul(dz,dz));
    }
    if (tid == 0){
      idxf[b*MM + 0] = 0;
      pos2[(size_t)(b*MM)*3+0] = qx;
      pos2[(size_t)(b*MM)*3+1] = qy;
      pos2[(size_t)(b*MM)*3+2] = qz;
    }
    int wv = tid >> 6;
    __syncthreads();
    for (int s = 1; s < MM; ++s){
      // lane-local TREE max over 8 u64 keys (depth 3)
      u64 t0 = umax64(((u64)__float_as_uint(MD[0])<<32)|LO[0], ((u64)__float_as_uint(MD[1])<<32)|LO[1]);
      u64 t1 = umax64(((u64)__float_as_uint(MD[2])<<32)|LO[2], ((u64)__float_as_uint(MD[3])<<32)|LO[3]);
      u64 t2 = umax64(((u64)__float_as_uint(MD[4])<<32)|LO[4], ((u64)__float_as_uint(MD[5])<<32)|LO[5]);
      u64 t3 = umax64(((u64)__float_as_uint(MD[6])<<32)|LO[6], ((u64)__float_as_uint(MD[7])<<32)|LO[7]);
      u64 kk = umax64(umax64(t0, t1), umax64(t2, t3));
      // full wave64 max reduce entirely in DPP (no LDS hops):
      // xor1, xor2, ror4, ror8 -> every lane of each 16-lane row has row max;
      // row_bcast15 + row_bcast31 -> lane 63 has wave max.
#define RED_DPP(CTRL) { \
      unsigned lo_ = (unsigned)kk, hi_ = (unsigned)(kk>>32); \
      unsigned plo = (unsigned)__builtin_amdgcn_update_dpp((int)lo_,(int)lo_,CTRL,0xF,0xF,false); \
      unsigned phi = (unsigned)__builtin_amdgcn_update_dpp((int)hi_,(int)hi_,CTRL,0xF,0xF,false); \
      u64 o = ((u64)phi<<32)|plo; kk = o > kk ? o : kk; }
      RED_DPP(0xB1)   // quad_perm [1,0,3,2] : xor1
      RED_DPP(0x4E)   // quad_perm [2,3,0,1] : xor2
      RED_DPP(0x124)  // row_ror:4
      RED_DPP(0x128)  // row_ror:8
      RED_DPP(0x142)  // row_bcast:15
      RED_DPP(0x143)  // row_bcast:31
#undef RED_DPP
      // cross-wave: lane63 of each wave writes its wave max; single barrier
      int par = s & 1;
      if ((tid & 63) == 63) wred[par*4 + wv] = kk;
      __syncthreads();
      const u64* wr = wred + par*4;
      u64 K = umax64(umax64(wr[0], wr[1]), umax64(wr[2], wr[3]));
      unsigned wp = ~(unsigned)K;
      float4 wc = pts4[wp];                 // broadcast ds_read_b128
      if (tid == 0){
        idxf[b*MM + s] = (int)wp;
        pos2[(size_t)(b*MM+s)*3+0] = wc.x;
        pos2[(size_t)(b*MM+s)*3+1] = wc.y;
        pos2[(size_t)(b*MM+s)*3+2] = wc.z;
      }
#pragma unroll
      for (int q = 0; q < 8; ++q){
        float dx = frn_sub(X[q],wc.x), dy = frn_sub(Y[q],wc.y), dz = frn_sub(Z[q],wc.z);
        float d = frn_add(frn_add(frn_mul(dx,dx), frn_mul(dy,dy)), frn_mul(dz,dz));
        MD[q] = fminf(MD[q], d);
      }
    }
  } else {
    int cid = blockIdx.x - 16;          // 0..255
    int b = cid >> 4;
    int rblk = (cid >> 1) & 7;
    int ch = cid & 1;
    float4* sm = (float4*)smem;         // 1024 * 16B
    const float* pos_b = pos + (size_t)b*NN*3;
    int i = rblk*256 + tid;
    u64* out = pknn1 + ((size_t)(b*NN + i)*2 + ch)*KNNK;
    knn_chunk_body<1024>(pos_b, rblk*256, ch*1024, sm, out, tid);
  }
}

// ---- K1: blocks 0..127 = merge1 (2-way), blocks 128..383 = knn2 chunks ----
__global__ __launch_bounds__(256) void k1_merge1_knn2(const u64* __restrict__ pknn1,
    int* __restrict__ idx1, const float* __restrict__ pos2, u64* __restrict__ pknn2){
  __shared__ __align__(16) float4 sm[256];
  int tid = threadIdx.x;
  if (blockIdx.x < 128){
    int row = blockIdx.x*256 + tid;     // 32768 rows
    const u64* A = pknn1 + (size_t)row*32;
    const u64* B = A + 16;
    int ia = 0, ib = 0;
    int* op = idx1 + (size_t)row*KNNK;
#pragma unroll
    for (int p = 0; p < KNNK; ++p){
      u64 ka = A[ia], kb = B[ib];
      if (ka < kb){ op[p] = (int)(unsigned)ka; ++ia; }
      else        { op[p] = (int)(unsigned)kb; ++ib; }
    }
  } else {
    int cid = blockIdx.x - 128;         // 0..255
    int b = cid >> 4;
    int rblk = (cid >> 2) & 3;
    int ch = cid & 3;
    const float* pos_b = pos2 + (size_t)b*MM*3;
    int i = rblk*256 + tid;
    u64* out = pknn2 + ((size_t)(b*MM + i)*4 + ch)*KNNK;
    knn_chunk_body<256>(pos_b, rblk*256, ch*256, sm, out, tid);
  }
}

// ---- K2: blocks 0..63 = merge2 (4-way), blocks 64..1087 = conv1 stats ----
__global__ __launch_bounds__(256) void k2_merge2_c1stats(const u64* __restrict__ pknn2,
    int* __restrict__ idx2, const float* __restrict__ pos, const int* __restrict__ idx1,
    const float* __restrict__ W1, const float* __restrict__ b1, float* __restrict__ stats1){
  __shared__ float red[4][64][2];
  int tid = threadIdx.x;
  if (blockIdx.x < 64){
    int row = blockIdx.x*256 + tid;     // 16384 rows
    const u64* L = pknn2 + (size_t)row*64;
    int o0=0, o1=0, o2=0, o3=0;
    int* op = idx2 + (size_t)row*KNNK;
#pragma unroll
    for (int p = 0; p < KNNK; ++p){
      u64 k0 = L[o0], k1 = L[16+o1], k2 = L[32+o2], k3 = L[48+o3];
      u64 m01 = k0 < k1 ? k0 : k1;
      u64 m23 = k2 < k3 ? k2 : k3;
      u64 m = m01 < m23 ? m01 : m23;
      op[p] = (int)(unsigned)m;
      o0 += (m == k0); o1 += (m == k1); o2 += (m == k2); o3 += (m == k3);
    }
    return;
  }
  int lane = tid & 63, wv = tid >> 6;
  int wave = (blockIdx.x - 64)*4 + wv;  // 0..4095, 8 rows each
  float w[6];
#pragma unroll
  for (int f = 0; f < 6; ++f) w[f] = W1[f*64 + lane];
  float bias = b1[lane];
  float ssum = 0.f, ssq = 0.f;
  for (int r = 0; r < 8; ++r){
    int row = wave*8 + r;
    int b = row >> 11, ii = row & 2047;
    const float* pi = pos + ((size_t)(b*NN + ii))*3;
    float xi = pi[0], yi = pi[1], zi = pi[2];
    const int* ip = idx1 + (size_t)row * KNNK;
#pragma unroll 4
    for (int k = 0; k < KNNK; ++k){
      int j = ip[k];
      const float* pj = pos + ((size_t)(b*NN + j))*3;
      float xj = pj[0], yj = pj[1], zj = pj[2];
      float y = bias;
      y = fmaf(xj, w[0], y); y = fmaf(yj, w[1], y); y = fmaf(zj, w[2], y);
      y = fmaf(xj - xi, w[3], y); y = fmaf(yj - yi, w[4], y); y = fmaf(zj - zi, w[5], y);
      ssum += y; ssq = fmaf(y, y, ssq);
    }
  }
  red[wv][lane][0] = ssum; red[wv][lane][1] = ssq;
  __syncthreads();
  if (tid < 64){
    float s = red[0][lane][0]+red[1][lane][0]+red[2][lane][0]+red[3][lane][0];
    float q = red[0][lane][1]+red[1][lane][1]+red[2][lane][1]+red[3][lane][1];
    atomicAdd(&stats1[lane], s);
    atomicAdd(&stats1[64+lane], q);
  }
}

__global__ __launch_bounds__(256) void conv1_apply_kernel(
    const float* __restrict__ pos, const int* __restrict__ idx1,
    const float* __restrict__ W1, const float* __restrict__ b1,
    const float* __restrict__ g1, const float* __restrict__ be1,
    const float* __restrict__ stats1, float* __restrict__ h){
  int lane = threadIdx.x & 63, wv = threadIdx.x >> 6;
  int wave = blockIdx.x*4 + wv;
  float w[6];
#pragma unroll
  for (int f = 0; f < 6; ++f) w[f] = W1[f*64 + lane];
  float bias = b1[lane];
  const float inv = 1.0f / (float)RC1;
  float mu = stats1[lane] * inv;
  float var = fmaxf(stats1[64+lane]*inv - mu*mu, 0.f);
  float sc = rsqrtf(var + 1e-5f) * g1[lane];
  float sh = be1[lane] - mu*sc;
  for (int r = 0; r < 8; ++r){
    int row = wave*8 + r;
    int b = row >> 11, ii = row & 2047;
    const float* pi = pos + ((size_t)(b*NN + ii))*3;
    float xi = pi[0], yi = pi[1], zi = pi[2];
    const int* ip = idx1 + (size_t)row * KNNK;
    float ymn = INFINITY, ymx = -INFINITY;
#pragma unroll 4
    for (int k = 0; k < KNNK; ++k){
      int j = ip[k];
      const float* pj = pos + ((size_t)(b*NN + j))*3;
      float xj = pj[0], yj = pj[1], zj = pj[2];
      float y = bias;
      y = fmaf(xj, w[0], y); y = fmaf(yj, w[1], y); y = fmaf(zj, w[2], y);
      y = fmaf(xj - xi, w[3], y); y = fmaf(yj - yi, w[4], y); y = fmaf(zj - zi, w[5], y);
      ymn = fminf(ymn, y); ymx = fmaxf(ymx, y);
    }
    h[((size_t)row << 6) + lane] = fmaxf(silu_f(fmaf(ymx, sc, sh)), silu_f(fmaf(ymn, sc, sh)));
  }
}

// ---- conv2a: 4 rows share each LDS weight read; double indirection replaces hs ----
__global__ __launch_bounds__(256) void conv2a_kernel(
    const float* __restrict__ h, const int* __restrict__ idxf,
    const float* __restrict__ pos2, const int* __restrict__ idx2,
    const float* __restrict__ W2a, const float* __restrict__ b2a,
    float* __restrict__ stats2a, __hip_bfloat16* __restrict__ y2a){
  __shared__ float Wl[67*128];
  __shared__ float red[4][64][4];
  for (int t = threadIdx.x; t < 67*128; t += 256) Wl[t] = W2a[t];
  __syncthreads();
  int lane = threadIdx.x & 63, wv = threadIdx.x >> 6;
  int wave = blockIdx.x*4 + wv;                 // 0..4095, 64 rows each
  float bias0 = b2a[lane], bias1 = b2a[64+lane];
  float ssum0=0, ssq0=0, ssum1=0, ssq1=0;
  for (int r4 = 0; r4 < 16; ++r4){
    int row0 = wave*64 + r4*4;
    int b = row0 >> 14;
    int m = (row0 >> 4) & 1023;
    int j0 = idx2[row0+0], j1 = idx2[row0+1], j2 = idx2[row0+2], j3 = idx2[row0+3];
    int q0 = idxf[b*MM + j0], q1 = idxf[b*MM + j1], q2 = idxf[b*MM + j2], q3 = idxf[b*MM + j3];
    const float4* h0 = (const float4*)(h + ((size_t)(b*NN + q0) << 6));
    const float4* h1 = (const float4*)(h + ((size_t)(b*NN + q1) << 6));
    const float4* h2 = (const float4*)(h + ((size_t)(b*NN + q2) << 6));
    const float4* h3 = (const float4*)(h + ((size_t)(b*NN + q3) << 6));
    float y00=bias0, y01=bias1, y10=bias0, y11=bias1;
    float y20=bias0, y21=bias1, y30=bias0, y31=bias1;
#define C2A_STEP(e, a0v, a1v, a2v, a3v) { \
      float w0_ = Wl[(e)*128 + lane], w1_ = Wl[(e)*128 + 64 + lane]; \
      y00 = fmaf(a0v, w0_, y00); y01 = fmaf(a0v, w1_, y01); \
      y10 = fmaf(a1v, w0_, y10); y11 = fmaf(a1v, w1_, y11); \
      y20 = fmaf(a2v, w0_, y20); y21 = fmaf(a2v, w1_, y21); \
      y30 = fmaf(a3v, w0_, y30); y31 = fmaf(a3v, w1_, y31); }
#pragma unroll
    for (int f4 = 0; f4 < 16; ++f4){
      float4 v0 = h0[f4], v1 = h1[f4], v2 = h2[f4], v3 = h3[f4];
      C2A_STEP(f4*4+0, v0.x, v1.x, v2.x, v3.x)
      C2A_STEP(f4*4+1, v0.y, v1.y, v2.y, v3.y)
      C2A_STEP(f4*4+2, v0.z, v1.z, v2.z, v3.z)
      C2A_STEP(f4*4+3, v0.w, v1.w, v2.w, v3.w)
    }
    const float* pm = pos2 + ((size_t)(b*MM + m))*3;
    float pmx = pm[0], pmy = pm[1], pmz = pm[2];
    const float* pj0 = pos2 + ((size_t)(b*MM + j0))*3;
    const float* pj1 = pos2 + ((size_t)(b*MM + j1))*3;
    const float* pj2 = pos2 + ((size_t)(b*MM + j2))*3;
    const float* pj3 = pos2 + ((size_t)(b*MM + j3))*3;
    C2A_STEP(64, pj0[0]-pmx, pj1[0]-pmx, pj2[0]-pmx, pj3[0]-pmx)
    C2A_STEP(65, pj0[1]-pmy, pj1[1]-pmy, pj2[1]-pmy, pj3[1]-pmy)
    C2A_STEP(66, pj0[2]-pmz, pj1[2]-pmz, pj2[2]-pmz, pj3[2]-pmz)
#undef C2A_STEP
    ssum0 += y00+y10+y20+y30;
    ssum1 += y01+y11+y21+y31;
    ssq0 = fmaf(y00,y00,fmaf(y10,y10,fmaf(y20,y20,fmaf(y30,y30,ssq0))));
    ssq1 = fmaf(y01,y01,fmaf(y11,y11,fmaf(y21,y21,fmaf(y31,y31,ssq1))));
    y2a[(size_t)(row0+0)*128 + lane]      = __float2bfloat16(y00);
    y2a[(size_t)(row0+0)*128 + 64 + lane] = __float2bfloat16(y01);
    y2a[(size_t)(row0+1)*128 + lane]      = __float2bfloat16(y10);
    y2a[(size_t)(row0+1)*128 + 64 + lane] = __float2bfloat16(y11);
    y2a[(size_t)(row0+2)*128 + lane]      = __float2bfloat16(y20);
    y2a[(size_t)(row0+2)*128 + 64 + lane] = __float2bfloat16(y21);
    y2a[(size_t)(row0+3)*128 + lane]      = __float2bfloat16(y30);
    y2a[(size_t)(row0+3)*128 + 64 + lane] = __float2bfloat16(y31);
  }
  red[wv][lane][0]=ssum0; red[wv][lane][1]=ssq0; red[wv][lane][2]=ssum1; red[wv][lane][3]=ssq1;
  __syncthreads();
  if (threadIdx.x < 64){
    float s0=0,q0=0,s1=0,q1=0;
#pragma unroll
    for (int v2=0; v2<4; ++v2){ s0+=red[v2][lane][0]; q0+=red[v2][lane][1]; s1+=red[v2][lane][2]; q1+=red[v2][lane][3]; }
    atomicAdd(&stats2a[lane], s0);      atomicAdd(&stats2a[128+lane], q0);
    atomicAdd(&stats2a[64+lane], s1);   atomicAdd(&stats2a[192+lane], q1);
  }
}

// ---- conv2b: 64x64 tiles, transposed activation staging, 4x4 thread tile ----
__global__ __launch_bounds__(256) void conv2b_kernel(
    const __hip_bfloat16* __restrict__ y2a, const float* __restrict__ stats2a,
    const float* __restrict__ g2a, const float* __restrict__ be2a,
    const float* __restrict__ W2b, const float* __restrict__ b2b,
    float* __restrict__ stats2b, unsigned* __restrict__ gmax, unsigned* __restrict__ gmin){
  __shared__ float Wl[128*64];
  __shared__ float aT[128*64];
  __shared__ float sc2a[128], sh2a[128];
  int tid = threadIdx.x;
  int ct = blockIdx.x & 3;
  int rb = blockIdx.x >> 2;                     // 0..511, 512 rows each
  int c0 = ct * 64;
  for (int t = tid; t < 128*64; t += 256){
    int kk = t >> 6, cc = t & 63;
    Wl[t] = W2b[kk*256 + c0 + cc];
  }
  if (tid < 128){
    const float inv = 1.0f / (float)RC2;
    float mu = stats2a[tid] * inv;
    float var = fmaxf(stats2a[128+tid]*inv - mu*mu, 0.f);
    float s = rsqrtf(var + 1e-5f) * g2a[tid];
    sc2a[tid] = s; sh2a[tid] = be2a[tid] - mu*s;
  }
  __syncthreads();
  int rg = tid & 15, cg = tid >> 4;
  float bb4[4];
#pragma unroll
  for (int j = 0; j < 4; ++j) bb4[j] = b2b[c0 + cg*4 + j];
  float vmn[4], vmx[4], ssum[4], ssq[4];
#pragma unroll
  for (int j = 0; j < 4; ++j){ vmn[j]=INFINITY; vmx[j]=-INFINITY; ssum[j]=0.f; ssq[j]=0.f; }
  int batch = rb >> 5;
  const unsigned short* y2u = (const unsigned short*)y2a;
  int srr = tid & 63, skq = tid >> 6;           // staging: row = srr, k-quarter = skq
  for (int tile = 0; tile < 8; ++tile){
    int row0 = rb*512 + tile*64;
    const unsigned short* src = y2u + (size_t)(row0 + srr)*128 + skq*32;
#pragma unroll
    for (int u = 0; u < 8; ++u){
      ushort4 v = *(const ushort4*)(src + u*4);
      int kk = skq*32 + u*4;
      float f0 = __uint_as_float((unsigned)v.x << 16);
      float f1 = __uint_as_float((unsigned)v.y << 16);
      float f2 = __uint_as_float((unsigned)v.z << 16);
      float f3 = __uint_as_float((unsigned)v.w << 16);
      aT[(kk+0)*64 + srr] = silu_f(fmaf(f0, sc2a[kk+0], sh2a[kk+0]));
      aT[(kk+1)*64 + srr] = silu_f(fmaf(f1, sc2a[kk+1], sh2a[kk+1]));
      aT[(kk+2)*64 + srr] = silu_f(fmaf(f2, sc2a[kk+2], sh2a[kk+2]));
      aT[(kk+3)*64 + srr] = silu_f(fmaf(f3, sc2a[kk+3], sh2a[kk+3]));
    }
    __syncthreads();
    float acc[4][4];
#pragma unroll
    for (int i = 0; i < 4; ++i)
#pragma unroll
      for (int j = 0; j < 4; ++j) acc[i][j] = 0.f;
#pragma unroll 4
    for (int kk = 0; kk < 128; ++kk){
      float4 av = *(const float4*)&aT[kk*64 + rg*4];
      float4 wv4 = *(const float4*)&Wl[kk*64 + cg*4];
      acc[0][0]=fmaf(av.x,wv4.x,acc[0][0]); acc[0][1]=fmaf(av.x,wv4.y,acc[0][1]);
      acc[0][2]=fmaf(av.x,wv4.z,acc[0][2]); acc[0][3]=fmaf(av.x,wv4.w,acc[0][3]);
      acc[1][0]=fmaf(av.y,wv4.x,acc[1][0]); acc[1][1]=fmaf(av.y,wv4.y,acc[1][1]);
      acc[1][2]=fmaf(av.y,wv4.z,acc[1][2]); acc[1][3]=fmaf(av.y,wv4.w,acc[1][3]);
      acc[2][0]=fmaf(av.z,wv4.x,acc[2][0]); acc[2][1]=fmaf(av.z,wv4.y,acc[2][1]);
      acc[2][2]=fmaf(av.z,wv4.z,acc[2][2]); acc[2][3]=fmaf(av.z,wv4.w,acc[2][3]);
      acc[3][0]=fmaf(av.w,wv4.x,acc[3][0]); acc[3][1]=fmaf(av.w,wv4.y,acc[3][1]);
      acc[3][2]=fmaf(av.w,wv4.z,acc[3][2]); acc[3][3]=fmaf(av.w,wv4.w,acc[3][3]);
    }
    __syncthreads();
#pragma unroll
    for (int i = 0; i < 4; ++i)
#pragma unroll
      for (int j = 0; j < 4; ++j){
        float y = acc[i][j] + bb4[j];
        vmn[j] = fminf(vmn[j], y); vmx[j] = fmaxf(vmx[j], y);
        ssum[j] += y; ssq[j] = fmaf(y, y, ssq[j]);
      }
  }
  float* scr = aT;   // 8192 floats scratch
#pragma unroll
  for (int j = 0; j < 4; ++j){
    scr[((0*16+rg)*16+cg)*4 + j] = vmn[j];
    scr[((1*16+rg)*16+cg)*4 + j] = vmx[j];
    scr[((2*16+rg)*16+cg)*4 + j] = ssum[j];
    scr[((3*16+rg)*16+cg)*4 + j] = ssq[j];
  }
  __syncthreads();
  if (tid < 64){
    int cg_ = tid >> 2, j_ = tid & 3;
    float mn = INFINITY, mx = -INFINITY, s = 0.f, q = 0.f;
    for (int r = 0; r < 16; ++r){
      mn = fminf(mn, scr[((0*16+r)*16+cg_)*4 + j_]);
      mx = fmaxf(mx, scr[((1*16+r)*16+cg_)*4 + j_]);
      s += scr[((2*16+r)*16+cg_)*4 + j_];
      q += scr[((3*16+r)*16+cg_)*4 + j_];
    }
    int c = c0 + cg_*4 + j_;
    atomicAdd(&stats2b[c], s);
    atomicAdd(&stats2b[256+c], q);
    atomicMaxF(&gmax[batch*256 + c], mx);
    atomicMinF(&gmin[batch*256 + c], mn);
  }
}

__global__ __launch_bounds__(256) void final_kernel(
    const float* __restrict__ stats2b, const unsigned* __restrict__ gmax,
    const unsigned* __restrict__ gmin, const float* __restrict__ g2b,
    const float* __restrict__ be2b, float* __restrict__ out){
  int t = blockIdx.x*256 + threadIdx.x;
  if (t >= NB*256) return;
  int c = t & 255;
  const float inv = 1.0f / (float)RC2;
  float mu = stats2b[c]*inv;
  float var = fmaxf(stats2b[256+c]*inv - mu*mu, 0.f);
  float sc = rsqrtf(var + 1e-5f)*g2b[c];
  float sh = be2b[c] - mu*sc;
  float mx = __uint_as_float(gmax[t]);
  float mn = __uint_as_float(gmin[t]);
  out[t] = fmaxf(silu_f(fmaf(mx, sc, sh)), silu_f(fmaf(mn, sc, sh)));
}

extern "C" void kernel_launch(void* const* d_in, const int* in_sizes, int n_in,
                              void* d_out, int out_size, void* d_ws, size_t ws_size,
                              hipStream_t stream){
  (void)in_sizes; (void)n_in; (void)out_size; (void)ws_size;
  const float* pos  = (const float*)d_in[0];
  const float* W1   = (const float*)d_in[1];
  const float* b1   = (const float*)d_in[2];
  const float* g1   = (const float*)d_in[3];
  const float* be1  = (const float*)d_in[4];
  const float* W2a  = (const float*)d_in[5];
  const float* b2a  = (const float*)d_in[6];
  const float* g2a  = (const float*)d_in[7];
  const float* be2a = (const float*)d_in[8];
  const float* W2b  = (const float*)d_in[9];
  const float* b2b  = (const float*)d_in[10];
  const float* g2b  = (const float*)d_in[11];
  const float* be2b = (const float*)d_in[12];

  char* w = (char*)d_ws;
  size_t off = 0;
  auto carve = [&](size_t bytes)->void*{ void* p = w + off; off += (bytes + 255) & ~(size_t)255; return p; };
  int*      idx1    = (int*)carve((size_t)NB*NN*KNNK*4);      // 2 MB
  float*    h       = (float*)carve((size_t)NB*NN*64*4);      // 8 MB
  int*      idxf    = (int*)carve((size_t)NB*MM*4);
  float*    pos2    = (float*)carve((size_t)NB*MM*3*4);
  int*      idx2    = (int*)carve((size_t)NB*MM*KNNK*4);      // 1 MB
  float*    stats1  = (float*)carve(128*4);
  float*    stats2a = (float*)carve(256*4);
  float*    stats2b = (float*)carve(512*4);
  unsigned* gmax    = (unsigned*)carve(4096*4);
  unsigned* gmin    = (unsigned*)carve(4096*4);
  __hip_bfloat16* y2a = (__hip_bfloat16*)carve((size_t)RC2*128*2);  // 64 MB
  // pknn buffers live inside the y2a region (dead before conv2a writes y2a)
  u64* pknn1 = (u64*)y2a;                          // 8 MB  (dead after K1)
  u64* pknn2 = (u64*)((char*)y2a + (32u<<20));     // 8 MB  (dead after K2)

  init_kernel<<<dim3(16), dim3(256), 0, stream>>>(stats1, stats2a, stats2b, gmax, gmin);
  k0_fps_knn1<<<dim3(272), dim3(256), 0, stream>>>(pos, idxf, pos2, pknn1);
  k1_merge1_knn2<<<dim3(384), dim3(256), 0, stream>>>(pknn1, idx1, pos2, pknn2);
  k2_merge2_c1stats<<<dim3(1088), dim3(256), 0, stream>>>(pknn2, idx2, pos, idx1, W1, b1, stats1);
  conv1_apply_kernel<<<dim3(1024), dim3(256), 0, stream>>>(pos, idx1, W1, b1, g1, be1, stats1, h);
  conv2a_kernel<<<dim3(1024), dim3(256), 0, stream>>>(h, idxf, pos2, idx2, W2a, b2a, stats2a, y2a);
  conv2b_kernel<<<dim3(2048), dim3(256), 0, stream>>>(y2a, stats2a, g2a, be2a, W2b, b2b, stats2b, gmax, gmin);
  final_kernel<<<dim3(16), dim3(256), 0, stream>>>(stats2b, gmax, gmin, g2b, be2b, (float*)d_out);
}

// Round 7
// 970.323 us; speedup vs baseline: 1.6245x; 1.2014x over previous
//
#include <hip/hip_runtime.h>
#include <hip/hip_bf16.h>

#define NB 16
#define NN 2048
#define KNNK 16
#define MM 1024
#define RC1 (NB*NN*KNNK)   // 524288 conv1 BN rows
#define RC2 (NB*MM*KNNK)   // 262144 conv2 BN rows

typedef unsigned long long u64;
typedef __attribute__((ext_vector_type(8))) short short8;
typedef __attribute__((ext_vector_type(4))) float f32x4;

__device__ __forceinline__ float frn_mul(float a, float b){ return __fmul_rn(a,b); }
__device__ __forceinline__ float frn_add(float a, float b){ return __fadd_rn(a,b); }
__device__ __forceinline__ float frn_sub(float a, float b){ return __fsub_rn(a,b); }
__device__ __forceinline__ float silu_f(float x){ return x / (1.0f + __expf(-x)); }
__device__ __forceinline__ u64 umax64(u64 a, u64 b){ return a > b ? a : b; }

__device__ __forceinline__ unsigned f32_sortable(float f){
  unsigned u = __float_as_uint(f);
  return u ^ ((unsigned)((int)u >> 31) | 0x80000000u);
}
// float -> bf16 RNE
__device__ __forceinline__ unsigned short f2bf(float f){
  unsigned u = __float_as_uint(f);
  return (unsigned short)((u + 0x7FFFu + ((u >> 16) & 1u)) >> 16);
}
__device__ __forceinline__ float bf2f(unsigned short h){
  return __uint_as_float(((unsigned)h) << 16);
}

__device__ __forceinline__ void atomicMaxF(unsigned* addr, float v){
  if (v >= 0.f) atomicMax((int*)addr, (int)__float_as_uint(v));
  else          atomicMin(addr, __float_as_uint(v));
}
__device__ __forceinline__ void atomicMinF(unsigned* addr, float v){
  if (v >= 0.f) atomicMin((int*)addr, (int)__float_as_uint(v));
  else          atomicMax(addr, __float_as_uint(v));
}

__global__ __launch_bounds__(256) void init_kernel(float* stats1, float* stats2a, float* stats2b,
                                                   unsigned* gmax, unsigned* gmin){
  int t = blockIdx.x*256 + threadIdx.x;
  if (t < 128) stats1[t] = 0.f;
  if (t < 256) stats2a[t] = 0.f;
  if (t < 512) stats2b[t] = 0.f;
  if (t < 4096){ gmax[t] = 0xFF800000u; gmin[t] = 0x7F800000u; }
}

// ---- knn chunk: 256 query threads vs CHUNK staged points; sorted u64 top-16 ----
template<int CHUNK>
__device__ __forceinline__ void knn_chunk_body(const float* __restrict__ pos_b, int qbase, int jbase,
                                               float4* sm, u64* __restrict__ out, int tid){
  for (int t = tid; t < CHUNK; t += 256){
    const float* p = pos_b + (size_t)(jbase + t)*3;
    float x = p[0], y = p[1], z = p[2];
    float n2 = frn_add(frn_add(frn_mul(x,x), frn_mul(y,y)), frn_mul(z,z));
    sm[t] = make_float4(x,y,z,n2);
  }
  __syncthreads();
  int i = qbase + tid;
  const float* qp = pos_b + (size_t)i*3;
  float xi = qp[0], yi = qp[1], zi = qp[2];
  float n2i = frn_add(frn_add(frn_mul(xi,xi), frn_mul(yi,yi)), frn_mul(zi,zi));
  u64 best[KNNK];
#pragma unroll
  for (int p = 0; p < KNNK; ++p) best[p] = ~0ull;
  for (int jj = 0; jj < CHUNK; ++jj){
    float4 v = sm[jj];
    float e = frn_add(frn_add(frn_mul(xi,v.x), frn_mul(yi,v.y)), frn_mul(zi,v.z));
    float d = frn_sub(frn_add(n2i, v.w), frn_mul(2.0f, e));
    u64 key = ((u64)f32_sortable(d) << 32) | (unsigned)(jbase + jj);
    if (key < best[KNNK-1]){
      u64 cur = key;
#pragma unroll
      for (int p = 0; p < KNNK; ++p){
        u64 mn = best[p] < cur ? best[p] : cur;
        u64 mx = best[p] < cur ? cur : best[p];
        best[p] = mn; cur = mx;
      }
    }
  }
#pragma unroll
  for (int p = 0; p < KNNK; ++p) out[p] = best[p];
}

// ---- K0: blocks 0..15 = FPS (no global stores in the serial loop; sel in LDS,
//          parallel epilogue), blocks 16..271 = knn1 chunks ----
__global__ __launch_bounds__(256) void k0_fps_knn1(const float* __restrict__ pos,
    int* __restrict__ idxf, float* __restrict__ pos2, u64* __restrict__ pknn1){
  __shared__ __align__(16) char smem[37*1024];
  int tid = threadIdx.x;
  if (blockIdx.x < 16){
    int b = blockIdx.x;
    float4* pts4 = (float4*)smem;                    // 2048 * 16B = 32 KB
    int* sel = (int*)(smem + 32*1024);               // 1024 ints = 4 KB
    u64* wred = (u64*)(smem + 32*1024 + 4096);       // [2][4]
    const float* pb = pos + (size_t)b*NN*3;
    float X[8], Y[8], Z[8], MD[8];
    unsigned LO[8];
#pragma unroll
    for (int q = 0; q < 8; ++q){
      int p = tid + 256*q;
      float x = pb[p*3+0], y = pb[p*3+1], z = pb[p*3+2];
      X[q] = x; Y[q] = y; Z[q] = z;
      LO[q] = ~(unsigned)p;
      pts4[p] = make_float4(x, y, z, 0.f);
    }
    float qx = pb[0], qy = pb[1], qz = pb[2];
#pragma unroll
    for (int q = 0; q < 8; ++q){
      float dx = frn_sub(X[q],qx), dy = frn_sub(Y[q],qy), dz = frn_sub(Z[q],qz);
      MD[q] = frn_add(frn_add(frn_mul(dx,dx), frn_mul(dy,dy)), frn_mul(dz,dz));
    }
    if (tid == 0) sel[0] = 0;
    int wv = tid >> 6;
    __syncthreads();
    for (int s = 1; s < MM; ++s){
      // lane-local TREE max over 8 u64 keys (depth 3)
      u64 t0 = umax64(((u64)__float_as_uint(MD[0])<<32)|LO[0], ((u64)__float_as_uint(MD[1])<<32)|LO[1]);
      u64 t1 = umax64(((u64)__float_as_uint(MD[2])<<32)|LO[2], ((u64)__float_as_uint(MD[3])<<32)|LO[3]);
      u64 t2 = umax64(((u64)__float_as_uint(MD[4])<<32)|LO[4], ((u64)__float_as_uint(MD[5])<<32)|LO[5]);
      u64 t3 = umax64(((u64)__float_as_uint(MD[6])<<32)|LO[6], ((u64)__float_as_uint(MD[7])<<32)|LO[7]);
      u64 kk = umax64(umax64(t0, t1), umax64(t2, t3));
      // full wave64 max reduce in DPP; lane 63 ends with wave max
#define RED_DPP(CTRL) { \
      unsigned lo_ = (unsigned)kk, hi_ = (unsigned)(kk>>32); \
      unsigned plo = (unsigned)__builtin_amdgcn_update_dpp((int)lo_,(int)lo_,CTRL,0xF,0xF,false); \
      unsigned phi = (unsigned)__builtin_amdgcn_update_dpp((int)hi_,(int)hi_,CTRL,0xF,0xF,false); \
      u64 o = ((u64)phi<<32)|plo; kk = o > kk ? o : kk; }
      RED_DPP(0xB1)   // quad_perm xor1
      RED_DPP(0x4E)   // quad_perm xor2
      RED_DPP(0x124)  // row_ror:4
      RED_DPP(0x128)  // row_ror:8
      RED_DPP(0x142)  // row_bcast:15
      RED_DPP(0x143)  // row_bcast:31
#undef RED_DPP
      int par = s & 1;
      if ((tid & 63) == 63) wred[par*4 + wv] = kk;
      __syncthreads();
      const u64* wr = wred + par*4;
      u64 K = umax64(umax64(wr[0], wr[1]), umax64(wr[2], wr[3]));
      unsigned wp = ~(unsigned)K;
      if (tid == 0) sel[s] = (int)wp;       // LDS only; no global stores in loop
      float4 wc = pts4[wp];                 // broadcast ds_read_b128
#pragma unroll
      for (int q = 0; q < 8; ++q){
        float dx = frn_sub(X[q],wc.x), dy = frn_sub(Y[q],wc.y), dz = frn_sub(Z[q],wc.z);
        float d = frn_add(frn_add(frn_mul(dx,dx), frn_mul(dy,dy)), frn_mul(dz,dz));
        MD[q] = fminf(MD[q], d);
      }
    }
    __syncthreads();
    // parallel epilogue: write idxf + pos2
    for (int m = tid; m < MM; m += 256){
      int j = sel[m];
      idxf[b*MM + m] = j;
      float4 c = pts4[j];
      pos2[(size_t)(b*MM+m)*3+0] = c.x;
      pos2[(size_t)(b*MM+m)*3+1] = c.y;
      pos2[(size_t)(b*MM+m)*3+2] = c.z;
    }
  } else {
    int cid = blockIdx.x - 16;          // 0..255
    int b = cid >> 4;
    int rblk = (cid >> 1) & 7;
    int ch = cid & 1;
    float4* sm = (float4*)smem;         // 1024 * 16B
    const float* pos_b = pos + (size_t)b*NN*3;
    int i = rblk*256 + tid;
    u64* out = pknn1 + ((size_t)(b*NN + i)*2 + ch)*KNNK;
    knn_chunk_body<1024>(pos_b, rblk*256, ch*1024, sm, out, tid);
  }
}

// ---- K1: blocks 0..127 = merge1 (2-way), blocks 128..383 = knn2 chunks ----
__global__ __launch_bounds__(256) void k1_merge1_knn2(const u64* __restrict__ pknn1,
    int* __restrict__ idx1, const float* __restrict__ pos2, u64* __restrict__ pknn2){
  __shared__ __align__(16) float4 sm[256];
  int tid = threadIdx.x;
  if (blockIdx.x < 128){
    int row = blockIdx.x*256 + tid;     // 32768 rows
    const u64* A = pknn1 + (size_t)row*32;
    const u64* B = A + 16;
    int ia = 0, ib = 0;
    int* op = idx1 + (size_t)row*KNNK;
#pragma unroll
    for (int p = 0; p < KNNK; ++p){
      u64 ka = A[ia], kb = B[ib];
      if (ka < kb){ op[p] = (int)(unsigned)ka; ++ia; }
      else        { op[p] = (int)(unsigned)kb; ++ib; }
    }
  } else {
    int cid = blockIdx.x - 128;         // 0..255
    int b = cid >> 4;
    int rblk = (cid >> 2) & 3;
    int ch = cid & 3;
    const float* pos_b = pos2 + (size_t)b*MM*3;
    int i = rblk*256 + tid;
    u64* out = pknn2 + ((size_t)(b*MM + i)*4 + ch)*KNNK;
    knn_chunk_body<256>(pos_b, rblk*256, ch*256, sm, out, tid);
  }
}

// ---- K2: blocks 0..63 = merge2 (4-way), blocks 64..1087 = conv1 stats ----
__global__ __launch_bounds__(256) void k2_merge2_c1stats(const u64* __restrict__ pknn2,
    int* __restrict__ idx2, const float* __restrict__ pos, const int* __restrict__ idx1,
    const float* __restrict__ W1, const float* __restrict__ b1, float* __restrict__ stats1){
  __shared__ float red[4][64][2];
  int tid = threadIdx.x;
  if (blockIdx.x < 64){
    int row = blockIdx.x*256 + tid;     // 16384 rows
    const u64* L = pknn2 + (size_t)row*64;
    int o0=0, o1=0, o2=0, o3=0;
    int* op = idx2 + (size_t)row*KNNK;
#pragma unroll
    for (int p = 0; p < KNNK; ++p){
      u64 k0 = L[o0], k1 = L[16+o1], k2 = L[32+o2], k3 = L[48+o3];
      u64 m01 = k0 < k1 ? k0 : k1;
      u64 m23 = k2 < k3 ? k2 : k3;
      u64 m = m01 < m23 ? m01 : m23;
      op[p] = (int)(unsigned)m;
      o0 += (m == k0); o1 += (m == k1); o2 += (m == k2); o3 += (m == k3);
    }
    return;
  }
  int lane = tid & 63, wv = tid >> 6;
  int wave = (blockIdx.x - 64)*4 + wv;  // 0..4095, 8 rows each
  float w[6];
#pragma unroll
  for (int f = 0; f < 6; ++f) w[f] = W1[f*64 + lane];
  float bias = b1[lane];
  float ssum = 0.f, ssq = 0.f;
  for (int r = 0; r < 8; ++r){
    int row = wave*8 + r;
    int b = row >> 11, ii = row & 2047;
    const float* pi = pos + ((size_t)(b*NN + ii))*3;
    float xi = pi[0], yi = pi[1], zi = pi[2];
    const int* ip = idx1 + (size_t)row * KNNK;
#pragma unroll 4
    for (int k = 0; k < KNNK; ++k){
      int j = ip[k];
      const float* pj = pos + ((size_t)(b*NN + j))*3;
      float xj = pj[0], yj = pj[1], zj = pj[2];
      float y = bias;
      y = fmaf(xj, w[0], y); y = fmaf(yj, w[1], y); y = fmaf(zj, w[2], y);
      y = fmaf(xj - xi, w[3], y); y = fmaf(yj - yi, w[4], y); y = fmaf(zj - zi, w[5], y);
      ssum += y; ssq = fmaf(y, y, ssq);
    }
  }
  red[wv][lane][0] = ssum; red[wv][lane][1] = ssq;
  __syncthreads();
  if (tid < 64){
    float s = red[0][lane][0]+red[1][lane][0]+red[2][lane][0]+red[3][lane][0];
    float q = red[0][lane][1]+red[1][lane][1]+red[2][lane][1]+red[3][lane][1];
    atomicAdd(&stats1[lane], s);
    atomicAdd(&stats1[64+lane], q);
  }
}

__global__ __launch_bounds__(256) void conv1_apply_kernel(
    const float* __restrict__ pos, const int* __restrict__ idx1,
    const float* __restrict__ W1, const float* __restrict__ b1,
    const float* __restrict__ g1, const float* __restrict__ be1,
    const float* __restrict__ stats1, float* __restrict__ h){
  int lane = threadIdx.x & 63, wv = threadIdx.x >> 6;
  int wave = blockIdx.x*4 + wv;
  float w[6];
#pragma unroll
  for (int f = 0; f < 6; ++f) w[f] = W1[f*64 + lane];
  float bias = b1[lane];
  const float inv = 1.0f / (float)RC1;
  float mu = stats1[lane] * inv;
  float var = fmaxf(stats1[64+lane]*inv - mu*mu, 0.f);
  float sc = rsqrtf(var + 1e-5f) * g1[lane];
  float sh = be1[lane] - mu*sc;
  for (int r = 0; r < 8; ++r){
    int row = wave*8 + r;
    int b = row >> 11, ii = row & 2047;
    const float* pi = pos + ((size_t)(b*NN + ii))*3;
    float xi = pi[0], yi = pi[1], zi = pi[2];
    const int* ip = idx1 + (size_t)row * KNNK;
    float ymn = INFINITY, ymx = -INFINITY;
#pragma unroll 4
    for (int k = 0; k < KNNK; ++k){
      int j = ip[k];
      const float* pj = pos + ((size_t)(b*NN + j))*3;
      float xj = pj[0], yj = pj[1], zj = pj[2];
      float y = bias;
      y = fmaf(xj, w[0], y); y = fmaf(yj, w[1], y); y = fmaf(zj, w[2], y);
      y = fmaf(xj - xi, w[3], y); y = fmaf(yj - yi, w[4], y); y = fmaf(zj - zi, w[5], y);
      ymn = fminf(ymn, y); ymx = fmaxf(ymx, y);
    }
    h[((size_t)row << 6) + lane] = fmaxf(silu_f(fmaf(ymx, sc, sh)), silu_f(fmaf(ymn, sc, sh)));
  }
}

// ---- conv2a: 4 rows share each LDS weight read; double indirection replaces hs ----
__global__ __launch_bounds__(256) void conv2a_kernel(
    const float* __restrict__ h, const int* __restrict__ idxf,
    const float* __restrict__ pos2, const int* __restrict__ idx2,
    const float* __restrict__ W2a, const float* __restrict__ b2a,
    float* __restrict__ stats2a, __hip_bfloat16* __restrict__ y2a){
  __shared__ float Wl[67*128];
  __shared__ float red[4][64][4];
  for (int t = threadIdx.x; t < 67*128; t += 256) Wl[t] = W2a[t];
  __syncthreads();
  int lane = threadIdx.x & 63, wv = threadIdx.x >> 6;
  int wave = blockIdx.x*4 + wv;                 // 0..4095, 64 rows each
  float bias0 = b2a[lane], bias1 = b2a[64+lane];
  float ssum0=0, ssq0=0, ssum1=0, ssq1=0;
  for (int r4 = 0; r4 < 16; ++r4){
    int row0 = wave*64 + r4*4;
    int b = row0 >> 14;
    int m = (row0 >> 4) & 1023;
    int j0 = idx2[row0+0], j1 = idx2[row0+1], j2 = idx2[row0+2], j3 = idx2[row0+3];
    int q0 = idxf[b*MM + j0], q1 = idxf[b*MM + j1], q2 = idxf[b*MM + j2], q3 = idxf[b*MM + j3];
    const float4* h0 = (const float4*)(h + ((size_t)(b*NN + q0) << 6));
    const float4* h1 = (const float4*)(h + ((size_t)(b*NN + q1) << 6));
    const float4* h2 = (const float4*)(h + ((size_t)(b*NN + q2) << 6));
    const float4* h3 = (const float4*)(h + ((size_t)(b*NN + q3) << 6));
    float y00=bias0, y01=bias1, y10=bias0, y11=bias1;
    float y20=bias0, y21=bias1, y30=bias0, y31=bias1;
#define C2A_STEP(e, a0v, a1v, a2v, a3v) { \
      float w0_ = Wl[(e)*128 + lane], w1_ = Wl[(e)*128 + 64 + lane]; \
      y00 = fmaf(a0v, w0_, y00); y01 = fmaf(a0v, w1_, y01); \
      y10 = fmaf(a1v, w0_, y10); y11 = fmaf(a1v, w1_, y11); \
      y20 = fmaf(a2v, w0_, y20); y21 = fmaf(a2v, w1_, y21); \
      y30 = fmaf(a3v, w0_, y30); y31 = fmaf(a3v, w1_, y31); }
#pragma unroll
    for (int f4 = 0; f4 < 16; ++f4){
      float4 v0 = h0[f4], v1 = h1[f4], v2 = h2[f4], v3 = h3[f4];
      C2A_STEP(f4*4+0, v0.x, v1.x, v2.x, v3.x)
      C2A_STEP(f4*4+1, v0.y, v1.y, v2.y, v3.y)
      C2A_STEP(f4*4+2, v0.z, v1.z, v2.z, v3.z)
      C2A_STEP(f4*4+3, v0.w, v1.w, v2.w, v3.w)
    }
    const float* pm = pos2 + ((size_t)(b*MM + m))*3;
    float pmx = pm[0], pmy = pm[1], pmz = pm[2];
    const float* pj0 = pos2 + ((size_t)(b*MM + j0))*3;
    const float* pj1 = pos2 + ((size_t)(b*MM + j1))*3;
    const float* pj2 = pos2 + ((size_t)(b*MM + j2))*3;
    const float* pj3 = pos2 + ((size_t)(b*MM + j3))*3;
    C2A_STEP(64, pj0[0]-pmx, pj1[0]-pmx, pj2[0]-pmx, pj3[0]-pmx)
    C2A_STEP(65, pj0[1]-pmy, pj1[1]-pmy, pj2[1]-pmy, pj3[1]-pmy)
    C2A_STEP(66, pj0[2]-pmz, pj1[2]-pmz, pj2[2]-pmz, pj3[2]-pmz)
#undef C2A_STEP
    ssum0 += y00+y10+y20+y30;
    ssum1 += y01+y11+y21+y31;
    ssq0 = fmaf(y00,y00,fmaf(y10,y10,fmaf(y20,y20,fmaf(y30,y30,ssq0))));
    ssq1 = fmaf(y01,y01,fmaf(y11,y11,fmaf(y21,y21,fmaf(y31,y31,ssq1))));
    y2a[(size_t)(row0+0)*128 + lane]      = __float2bfloat16(y00);
    y2a[(size_t)(row0+0)*128 + 64 + lane] = __float2bfloat16(y01);
    y2a[(size_t)(row0+1)*128 + lane]      = __float2bfloat16(y10);
    y2a[(size_t)(row0+1)*128 + 64 + lane] = __float2bfloat16(y11);
    y2a[(size_t)(row0+2)*128 + lane]      = __float2bfloat16(y20);
    y2a[(size_t)(row0+2)*128 + 64 + lane] = __float2bfloat16(y21);
    y2a[(size_t)(row0+3)*128 + lane]      = __float2bfloat16(y30);
    y2a[(size_t)(row0+3)*128 + 64 + lane] = __float2bfloat16(y31);
  }
  red[wv][lane][0]=ssum0; red[wv][lane][1]=ssq0; red[wv][lane][2]=ssum1; red[wv][lane][3]=ssq1;
  __syncthreads();
  if (threadIdx.x < 64){
    float s0=0,q0=0,s1=0,q1=0;
#pragma unroll
    for (int v2=0; v2<4; ++v2){ s0+=red[v2][lane][0]; q0+=red[v2][lane][1]; s1+=red[v2][lane][2]; q1+=red[v2][lane][3]; }
    atomicAdd(&stats2a[lane], s0);      atomicAdd(&stats2a[128+lane], q0);
    atomicAdd(&stats2a[64+lane], s1);   atomicAdd(&stats2a[192+lane], q1);
  }
}

// ---- conv2b: MFMA 16x16x32 bf16. Block = 512 rows x 64 cols; A staged per
//      64-row tile (BN+SiLU -> bf16, XOR-swizzled LDS); B frags in registers. ----
__global__ __launch_bounds__(256) void conv2b_kernel(
    const __hip_bfloat16* __restrict__ y2a, const float* __restrict__ stats2a,
    const float* __restrict__ g2a, const float* __restrict__ be2a,
    const float* __restrict__ W2b, const float* __restrict__ b2b,
    float* __restrict__ stats2b, unsigned* __restrict__ gmax, unsigned* __restrict__ gmin){
  __shared__ __align__(16) char Albs[64*256];   // 64 rows x 128 k bf16, swizzled
  __shared__ __align__(16) char Btbs[64*256];   // 64 cols x 128 k bf16
  __shared__ float sc2a[128], sh2a[128];
  int tid = threadIdx.x;
  int lane = tid & 63, wvi = tid >> 6;
  int ct = blockIdx.x & 3;
  int rb = blockIdx.x >> 2;                     // 0..511, 512 rows each
  int c0 = ct * 64;
  int batch = rb >> 5;
  if (tid < 128){
    const float inv = 1.0f / (float)RC2;
    float mu = stats2a[tid] * inv;
    float var = fmaxf(stats2a[128+tid]*inv - mu*mu, 0.f);
    float s = rsqrtf(var + 1e-5f) * g2a[tid];
    sc2a[tid] = s; sh2a[tid] = be2a[tid] - mu*s;
  }
  // stage B^T (bf16): col cc, k-chunks u0, u0+4, u0+8, u0+12
  {
    int cc = tid & 63, u0 = tid >> 6;
#pragma unroll
    for (int i = 0; i < 4; ++i){
      int u = u0 + i*4;
      unsigned short hb[8];
#pragma unroll
      for (int e = 0; e < 8; ++e) hb[e] = f2bf(W2b[(size_t)(u*8+e)*256 + c0 + cc]);
      *(short8*)(Btbs + cc*256 + u*16) = *(short8*)hb;
    }
  }
  __syncthreads();
  // per-wave B fragments (wave covers cols c0 + wvi*16 .. +16), 4 k-chunks
  short8 bfrag[4];
#pragma unroll
  for (int kb4 = 0; kb4 < 4; ++kb4){
    int col_local = wvi*16 + (lane & 15);
    bfrag[kb4] = *(short8*)(Btbs + col_local*256 + kb4*64 + (lane>>4)*16);
  }
  float bb = b2b[c0 + wvi*16 + (lane & 15)];
  float vmn = INFINITY, vmx = -INFINITY, ssum = 0.f, ssq = 0.f;
  const unsigned short* y2u = (const unsigned short*)y2a;
  int sr = tid & 63, su = tid >> 6;             // staging: row sr, k-chunk su+4i
  for (int tile = 0; tile < 8; ++tile){
    int row0 = rb*512 + tile*64;
    if (tile > 0) __syncthreads();              // protect A overwrite
#pragma unroll
    for (int i = 0; i < 4; ++i){
      int u = su + i*4;
      short8 v = *(const short8*)(y2u + (size_t)(row0 + sr)*128 + u*8);
      unsigned short ha[8];
#pragma unroll
      for (int e = 0; e < 8; ++e){
        int k = u*8 + e;
        float f = bf2f((unsigned short)v[e]);
        ha[e] = f2bf(silu_f(fmaf(f, sc2a[k], sh2a[k])));
      }
      *(short8*)(Albs + sr*256 + ((u*16) ^ ((sr & 7) << 4))) = *(short8*)ha;
    }
    __syncthreads();
    // compute: 4 slabs of 16 rows; wave's cols fixed
#pragma unroll
    for (int sl = 0; sl < 4; ++sl){
      f32x4 acc = {0.f, 0.f, 0.f, 0.f};
#pragma unroll
      for (int kb4 = 0; kb4 < 4; ++kb4){
        int r = sl*16 + (lane & 15);
        short8 afrag = *(short8*)(Albs + r*256 + ((kb4*64 + (lane>>4)*16) ^ ((r & 7) << 4)));
        acc = __builtin_amdgcn_mfma_f32_16x16x32_bf16(afrag, bfrag[kb4], acc, 0, 0, 0);
      }
#pragma unroll
      for (int j = 0; j < 4; ++j){
        float y = acc[j] + bb;
        vmn = fminf(vmn, y); vmx = fmaxf(vmx, y);
        ssum += y; ssq = fmaf(y, y, ssq);
      }
    }
  }
  // reduce across the 4 lanes sharing a col (lane, lane+16, +32, +48)
#pragma unroll
  for (int off = 16; off <= 32; off += 16){
    vmn  = fminf(vmn,  __shfl_xor(vmn,  off));
    vmx  = fmaxf(vmx,  __shfl_xor(vmx,  off));
    ssum = ssum + __shfl_xor(ssum, off);
    ssq  = ssq  + __shfl_xor(ssq,  off);
  }
  if ((lane >> 4) == 0){
    int c = c0 + wvi*16 + lane;
    atomicAdd(&stats2b[c], ssum);
    atomicAdd(&stats2b[256+c], ssq);
    atomicMaxF(&gmax[batch*256 + c], vmx);
    atomicMinF(&gmin[batch*256 + c], vmn);
  }
}

__global__ __launch_bounds__(256) void final_kernel(
    const float* __restrict__ stats2b, const unsigned* __restrict__ gmax,
    const unsigned* __restrict__ gmin, const float* __restrict__ g2b,
    const float* __restrict__ be2b, float* __restrict__ out){
  int t = blockIdx.x*256 + threadIdx.x;
  if (t >= NB*256) return;
  int c = t & 255;
  const float inv = 1.0f / (float)RC2;
  float mu = stats2b[c]*inv;
  float var = fmaxf(stats2b[256+c]*inv - mu*mu, 0.f);
  float sc = rsqrtf(var + 1e-5f)*g2b[c];
  float sh = be2b[c] - mu*sc;
  float mx = __uint_as_float(gmax[t]);
  float mn = __uint_as_float(gmin[t]);
  out[t] = fmaxf(silu_f(fmaf(mx, sc, sh)), silu_f(fmaf(mn, sc, sh)));
}

extern "C" void kernel_launch(void* const* d_in, const int* in_sizes, int n_in,
                              void* d_out, int out_size, void* d_ws, size_t ws_size,
                              hipStream_t stream){
  (void)in_sizes; (void)n_in; (void)out_size; (void)ws_size;
  const float* pos  = (const float*)d_in[0];
  const float* W1   = (const float*)d_in[1];
  const float* b1   = (const float*)d_in[2];
  const float* g1   = (const float*)d_in[3];
  const float* be1  = (const float*)d_in[4];
  const float* W2a  = (const float*)d_in[5];
  const float* b2a  = (const float*)d_in[6];
  const float* g2a  = (const float*)d_in[7];
  const float* be2a = (const float*)d_in[8];
  const float* W2b  = (const float*)d_in[9];
  const float* b2b  = (const float*)d_in[10];
  const float* g2b  = (const float*)d_in[11];
  const float* be2b = (const float*)d_in[12];

  char* w = (char*)d_ws;
  size_t off = 0;
  auto carve = [&](size_t bytes)->void*{ void* p = w + off; off += (bytes + 255) & ~(size_t)255; return p; };
  int*      idx1    = (int*)carve((size_t)NB*NN*KNNK*4);      // 2 MB
  float*    h       = (float*)carve((size_t)NB*NN*64*4);      // 8 MB
  int*      idxf    = (int*)carve((size_t)NB*MM*4);
  float*    pos2    = (float*)carve((size_t)NB*MM*3*4);
  int*      idx2    = (int*)carve((size_t)NB*MM*KNNK*4);      // 1 MB
  float*    stats1  = (float*)carve(128*4);
  float*    stats2a = (float*)carve(256*4);
  float*    stats2b = (float*)carve(512*4);
  unsigned* gmax    = (unsigned*)carve(4096*4);
  unsigned* gmin    = (unsigned*)carve(4096*4);
  __hip_bfloat16* y2a = (__hip_bfloat16*)carve((size_t)RC2*128*2);  // 64 MB
  // pknn buffers live inside the y2a region (dead before conv2a writes y2a)
  u64* pknn1 = (u64*)y2a;                          // 8 MB  (dead after K1)
  u64* pknn2 = (u64*)((char*)y2a + (32u<<20));     // 8 MB  (dead after K2)

  init_kernel<<<dim3(16), dim3(256), 0, stream>>>(stats1, stats2a, stats2b, gmax, gmin);
  k0_fps_knn1<<<dim3(272), dim3(256), 0, stream>>>(pos, idxf, pos2, pknn1);
  k1_merge1_knn2<<<dim3(384), dim3(256), 0, stream>>>(pknn1, idx1, pos2, pknn2);
  k2_merge2_c1stats<<<dim3(1088), dim3(256), 0, stream>>>(pknn2, idx2, pos, idx1, W1, b1, stats1);
  conv1_apply_kernel<<<dim3(1024), dim3(256), 0, stream>>>(pos, idx1, W1, b1, g1, be1, stats1, h);
  conv2a_kernel<<<dim3(1024), dim3(256), 0, stream>>>(h, idxf, pos2, idx2, W2a, b2a, stats2a, y2a);
  conv2b_kernel<<<dim3(2048), dim3(256), 0, stream>>>(y2a, stats2a, g2a, be2a, W2b, b2b, stats2b, gmax, gmin);
  final_kernel<<<dim3(16), dim3(256), 0, stream>>>(stats2b, gmax, gmin, g2b, be2b, (float*)d_out);
}